// Round 3
// baseline (726.262 us; speedup 1.0000x reference)
//
#include <hip/hip_runtime.h>
#include <hip/hip_bf16.h>

#define NN 100000
#define NE 1600000
#define NODE_D 64
#define EDGE_D 48
#define U_D 32
#define IN_D 144
#define HID 128
#define OUT_D 64
#define BM 64
#define S0 152   // act0 row stride (ushort cols)
#define S1 136   // act1 row stride

typedef __attribute__((ext_vector_type(8))) short bf16x8;
typedef __attribute__((ext_vector_type(4))) float f32x4;

__device__ __forceinline__ short f2bs(float f) {
  union { __hip_bfloat16 h; short s; } v;
  v.h = __float2bfloat16(f);
  return v.s;
}

__device__ __forceinline__ void st4(unsigned short* p, float4 v) {
  unsigned a = (unsigned)(unsigned short)f2bs(v.x) | ((unsigned)(unsigned short)f2bs(v.y) << 16);
  unsigned b = (unsigned)(unsigned short)f2bs(v.z) | ((unsigned)(unsigned short)f2bs(v.w) << 16);
  *reinterpret_cast<uint2*>(p) = make_uint2(a, b);
}

// ---------------- pass 1: histogram of source nodes ----------------
__global__ __launch_bounds__(256) void hist_kernel(const int* __restrict__ src,
                                                   int* __restrict__ hist) {
  int e = blockIdx.x * 256 + threadIdx.x;
  if (e >= NE) return;
  atomicAdd(&hist[src[e]], 1);
}

// ---------------- pass 2: exclusive scan (single block) ----------------
#define SCAN_T 1024
__global__ __launch_bounds__(SCAN_T) void scan_kernel(const int* __restrict__ hist,
                                                      int* __restrict__ offsets,
                                                      int* __restrict__ cursor) {
  __shared__ int wsum[16];
  const int tid = threadIdx.x;
  const int chunk = (NN + SCAN_T - 1) / SCAN_T;  // 98
  const int start = tid * chunk;
  int local = 0;
  for (int i = 0; i < chunk; ++i) {
    int idx = start + i;
    if (idx < NN) local += hist[idx];
  }
  int lane = tid & 63, wave = tid >> 6;
  int v = local;
  for (int d = 1; d < 64; d <<= 1) {
    int t = __shfl_up(v, d, 64);
    if (lane >= d) v += t;
  }
  if (lane == 63) wsum[wave] = v;
  __syncthreads();
  if (wave == 0) {
    int w = (lane < 16) ? wsum[lane] : 0;
    for (int d = 1; d < 16; d <<= 1) {
      int t = __shfl_up(w, d, 64);
      if (lane >= d) w += t;
    }
    if (lane < 16) wsum[lane] = w;
  }
  __syncthreads();
  int wave_prefix = (wave > 0) ? wsum[wave - 1] : 0;
  int excl = wave_prefix + v - local;
  for (int i = 0; i < chunk; ++i) {
    int idx = start + i;
    if (idx < NN) {
      offsets[idx] = excl;
      cursor[idx] = excl;
      excl += hist[idx];
    }
  }
}

// ---------------- pass 3: build permutation (edge ids grouped by node) ----------------
__global__ __launch_bounds__(256) void permute_kernel(const int* __restrict__ src,
                                                      int* __restrict__ cursor,
                                                      int* __restrict__ perm) {
  int e = blockIdx.x * 256 + threadIdx.x;
  if (e >= NE) return;
  int s = src[e];
  int pos = atomicAdd(&cursor[s], 1);
  perm[pos] = e;
}

// ---------------- pass 4: per-node gather + mean (bf16 out), 1 wave/node ----------------
__global__ __launch_bounds__(256) void gather_mean_kernel(
    const float* __restrict__ ea, const int* __restrict__ perm,
    const int* __restrict__ hist, const int* __restrict__ offsets,
    unsigned short* __restrict__ mean) {
  int node = (blockIdx.x * 256 + threadIdx.x) >> 6;
  int lane = threadIdx.x & 63;
  if (node >= NN) return;
  const int deg = hist[node];
  const int off = offsets[node];
  if (lane < 48) {
    float acc = 0.f;
    for (int j = 0; j < deg; ++j) {
      int e = perm[off + j];
      acc += ea[(size_t)e * EDGE_D + lane];
    }
    float m = acc / (float)(deg > 0 ? deg : 1);
    mean[(size_t)node * EDGE_D + lane] = (unsigned short)f2bs(m);
  }
}

// ---------------- pass 5: fused concat + 3-layer MLP (MFMA) ----------------
__global__ __launch_bounds__(256) void mlp_kernel(
    const float* __restrict__ x, const unsigned short* __restrict__ mean,
    const float* __restrict__ u, const int* __restrict__ batch,
    const float* __restrict__ W1, const float* __restrict__ b1,
    const float* __restrict__ W2, const float* __restrict__ b2,
    const float* __restrict__ W3, const float* __restrict__ b3,
    float* __restrict__ out) {
  __shared__ unsigned short act0[BM][S0];  // comb (144 cols), later h2 (128 cols)
  __shared__ unsigned short act1[BM][S1];  // h1 (128 cols)

  const int tid = threadIdx.x;
  const int lane = tid & 63;
  const int wid = tid >> 6;
  const int lr = lane & 15;
  const int lg = lane >> 4;
  const int node0 = blockIdx.x * BM;

  const bf16x8 az = {0, 0, 0, 0, 0, 0, 0, 0};

  // ---- stage comb = [x | v_e | u[batch]] as bf16 ----
  for (int i = tid; i < BM * (NODE_D / 4); i += 256) {
    int r = i >> 4, q = i & 15;
    int node = node0 + r;
    float4 v = make_float4(0.f, 0.f, 0.f, 0.f);
    if (node < NN) v = reinterpret_cast<const float4*>(x)[(size_t)node * 16 + q];
    st4(&act0[r][q * 4], v);
  }
  for (int i = tid; i < BM * (EDGE_D / 4); i += 256) {
    int r = i / 12, q = i - r * 12;
    int node = node0 + r;
    uint2 v = make_uint2(0, 0);
    if (node < NN) v = *reinterpret_cast<const uint2*>(&mean[(size_t)node * EDGE_D + q * 4]);
    *reinterpret_cast<uint2*>(&act0[r][NODE_D + q * 4]) = v;
  }
  for (int i = tid; i < BM * (U_D / 4); i += 256) {
    int r = i >> 3, q = i & 7;
    int node = node0 + r;
    float4 v = make_float4(0.f, 0.f, 0.f, 0.f);
    if (node < NN) {
      int b = batch[node];
      v = reinterpret_cast<const float4*>(u)[(size_t)b * 8 + q];
    }
    st4(&act0[r][NODE_D + EDGE_D + q * 4], v);
  }
  __syncthreads();

  // ---- layer 1: [64,144] @ [144,128] + b1, relu -> act1 ----
  {
    const int n0 = wid * 32;
    bf16x8 wf[5][2];
#pragma unroll
    for (int t = 0; t < 5; ++t) {
#pragma unroll
      for (int nf = 0; nf < 2; ++nf) {
        const int kb = t * 32 + lg * 8;
        const int n = n0 + nf * 16 + lr;
        bf16x8 r = az;
#pragma unroll
        for (int j = 0; j < 8; ++j) {
          int k = kb + j;
          if (k < IN_D) r[j] = f2bs(W1[(size_t)k * HID + n]);
        }
        wf[t][nf] = r;
      }
    }
    float bias0 = b1[n0 + lr], bias1 = b1[n0 + 16 + lr];
    f32x4 acc[4][2];
#pragma unroll
    for (int mf = 0; mf < 4; ++mf) {
      acc[mf][0] = (f32x4){bias0, bias0, bias0, bias0};
      acc[mf][1] = (f32x4){bias1, bias1, bias1, bias1};
    }
#pragma unroll
    for (int t = 0; t < 5; ++t) {
#pragma unroll
      for (int mf = 0; mf < 4; ++mf) {
        bf16x8 a;
        if (t < 4) {
          a = *reinterpret_cast<const bf16x8*>(&act0[mf * 16 + lr][t * 32 + lg * 8]);
        } else {
          a = az;
          if (lg < 2)
            a = *reinterpret_cast<const bf16x8*>(&act0[mf * 16 + lr][128 + lg * 8]);
        }
        acc[mf][0] = __builtin_amdgcn_mfma_f32_16x16x32_bf16(a, wf[t][0], acc[mf][0], 0, 0, 0);
        acc[mf][1] = __builtin_amdgcn_mfma_f32_16x16x32_bf16(a, wf[t][1], acc[mf][1], 0, 0, 0);
      }
    }
#pragma unroll
    for (int mf = 0; mf < 4; ++mf)
#pragma unroll
      for (int nf = 0; nf < 2; ++nf)
#pragma unroll
        for (int r = 0; r < 4; ++r)
          act1[mf * 16 + lg * 4 + r][n0 + nf * 16 + lr] =
              (unsigned short)f2bs(fmaxf(acc[mf][nf][r], 0.f));
  }
  __syncthreads();

  // ---- layer 2: [64,128] @ [128,128] + b2, relu -> act0 ----
  {
    const int n0 = wid * 32;
    bf16x8 wf[4][2];
#pragma unroll
    for (int t = 0; t < 4; ++t) {
#pragma unroll
      for (int nf = 0; nf < 2; ++nf) {
        const int kb = t * 32 + lg * 8;
        const int n = n0 + nf * 16 + lr;
        bf16x8 r;
#pragma unroll
        for (int j = 0; j < 8; ++j) r[j] = f2bs(W2[(size_t)(kb + j) * HID + n]);
        wf[t][nf] = r;
      }
    }
    float bias0 = b2[n0 + lr], bias1 = b2[n0 + 16 + lr];
    f32x4 acc[4][2];
#pragma unroll
    for (int mf = 0; mf < 4; ++mf) {
      acc[mf][0] = (f32x4){bias0, bias0, bias0, bias0};
      acc[mf][1] = (f32x4){bias1, bias1, bias1, bias1};
    }
#pragma unroll
    for (int t = 0; t < 4; ++t) {
#pragma unroll
      for (int mf = 0; mf < 4; ++mf) {
        bf16x8 a = *reinterpret_cast<const bf16x8*>(&act1[mf * 16 + lr][t * 32 + lg * 8]);
        acc[mf][0] = __builtin_amdgcn_mfma_f32_16x16x32_bf16(a, wf[t][0], acc[mf][0], 0, 0, 0);
        acc[mf][1] = __builtin_amdgcn_mfma_f32_16x16x32_bf16(a, wf[t][1], acc[mf][1], 0, 0, 0);
      }
    }
    __syncthreads();
#pragma unroll
    for (int mf = 0; mf < 4; ++mf)
#pragma unroll
      for (int nf = 0; nf < 2; ++nf)
#pragma unroll
        for (int r = 0; r < 4; ++r)
          act0[mf * 16 + lg * 4 + r][n0 + nf * 16 + lr] =
              (unsigned short)f2bs(fmaxf(acc[mf][nf][r], 0.f));
  }
  __syncthreads();

  // ---- layer 3: [64,128] @ [128,64] + b3 -> out (f32) ----
  {
    const int n0 = wid * 16;
    bf16x8 wf[4];
#pragma unroll
    for (int t = 0; t < 4; ++t) {
      const int kb = t * 32 + lg * 8;
      const int n = n0 + lr;
      bf16x8 r;
#pragma unroll
      for (int j = 0; j < 8; ++j) r[j] = f2bs(W3[(size_t)(kb + j) * OUT_D + n]);
      wf[t] = r;
    }
    float bias = b3[n0 + lr];
    f32x4 acc[4];
#pragma unroll
    for (int mf = 0; mf < 4; ++mf) acc[mf] = (f32x4){bias, bias, bias, bias};
#pragma unroll
    for (int t = 0; t < 4; ++t) {
#pragma unroll
      for (int mf = 0; mf < 4; ++mf) {
        bf16x8 a = *reinterpret_cast<const bf16x8*>(&act0[mf * 16 + lr][t * 32 + lg * 8]);
        acc[mf] = __builtin_amdgcn_mfma_f32_16x16x32_bf16(a, wf[t], acc[mf], 0, 0, 0);
      }
    }
#pragma unroll
    for (int mf = 0; mf < 4; ++mf)
#pragma unroll
      for (int r = 0; r < 4; ++r) {
        int node = node0 + mf * 16 + lg * 4 + r;
        if (node < NN) out[(size_t)node * OUT_D + n0 + lr] = acc[mf][r];
      }
  }
}

extern "C" void kernel_launch(void* const* d_in, const int* in_sizes, int n_in,
                              void* d_out, int out_size, void* d_ws, size_t ws_size,
                              hipStream_t stream) {
  const float* x   = (const float*)d_in[0];
  const int* ei    = (const int*)d_in[1];    // [2, NE]; row 0 = source nodes
  const float* ea  = (const float*)d_in[2];
  const float* u   = (const float*)d_in[3];
  const int* batch = (const int*)d_in[4];
  const float* W1  = (const float*)d_in[5];
  const float* b1  = (const float*)d_in[6];
  const float* W2  = (const float*)d_in[7];
  const float* b2  = (const float*)d_in[8];
  const float* W3  = (const float*)d_in[9];
  const float* b3  = (const float*)d_in[10];
  float* out = (float*)d_out;

  // workspace layout (17.2 MB total)
  unsigned short* mean = (unsigned short*)d_ws;            // NN*48 bf16
  int* hist    = (int*)(mean + (size_t)NN * EDGE_D);       // NN
  int* offsets = hist + NN;                                // NN
  int* cursor  = offsets + NN;                             // NN
  int* perm    = cursor + NN;                              // NE

  hipMemsetAsync(hist, 0, NN * sizeof(int), stream);

  hist_kernel<<<(NE + 255) / 256, 256, 0, stream>>>(ei, hist);
  scan_kernel<<<1, SCAN_T, 0, stream>>>(hist, offsets, cursor);
  permute_kernel<<<(NE + 255) / 256, 256, 0, stream>>>(ei, cursor, perm);
  gather_mean_kernel<<<(NN * 64 + 255) / 256, 256, 0, stream>>>(ea, perm, hist, offsets, mean);
  mlp_kernel<<<(NN + BM - 1) / BM, 256, 0, stream>>>(x, mean, u, batch,
                                                     W1, b1, W2, b2, W3, b3, out);
}

// Round 4
// 339.709 us; speedup vs baseline: 2.1379x; 2.1379x over previous
//
#include <hip/hip_runtime.h>
#include <hip/hip_bf16.h>

#define NN 100000
#define NE 1600000
#define NODE_D 64
#define EDGE_D 48
#define U_D 32
#define IN_D 144
#define HID 128
#define OUT_D 64
#define BM 64
#define S0 152   // act0 row stride (ushort cols)
#define S1 136   // act1 row stride
#define SCAN_BS 1024
#define SCAN_NB ((NN + SCAN_BS - 1) / SCAN_BS)  // 98

typedef __attribute__((ext_vector_type(8))) short bf16x8;
typedef __attribute__((ext_vector_type(4))) float f32x4;

__device__ __forceinline__ short f2bs(float f) {
  union { __hip_bfloat16 h; short s; } v;
  v.h = __float2bfloat16(f);
  return v.s;
}

__device__ __forceinline__ void st4(unsigned short* p, float4 v) {
  unsigned a = (unsigned)(unsigned short)f2bs(v.x) | ((unsigned)(unsigned short)f2bs(v.y) << 16);
  unsigned b = (unsigned)(unsigned short)f2bs(v.z) | ((unsigned)(unsigned short)f2bs(v.w) << 16);
  *reinterpret_cast<uint2*>(p) = make_uint2(a, b);
}

// ---------------- pass 1: histogram of source nodes ----------------
__global__ __launch_bounds__(256) void hist_kernel(const int* __restrict__ src,
                                                   int* __restrict__ hist) {
  int e = blockIdx.x * 256 + threadIdx.x;
  if (e >= NE) return;
  atomicAdd(&hist[src[e]], 1);
}

// ---------------- pass 2a: per-block sums of hist ----------------
__global__ __launch_bounds__(256) void bsum_kernel(const int* __restrict__ hist,
                                                   int* __restrict__ bsum) {
  const int b = blockIdx.x, tid = threadIdx.x;
  const int base = b * SCAN_BS + tid * 4;
  int4 v = make_int4(0, 0, 0, 0);
  if (base + 3 < NN) v = *reinterpret_cast<const int4*>(&hist[base]);
  else {
    int t[4] = {0, 0, 0, 0};
    for (int k = 0; k < 4; ++k) if (base + k < NN) t[k] = hist[base + k];
    v = make_int4(t[0], t[1], t[2], t[3]);
  }
  int s = v.x + v.y + v.z + v.w;
  for (int d = 32; d; d >>= 1) s += __shfl_down(s, d, 64);
  __shared__ int ws[4];
  if ((tid & 63) == 0) ws[tid >> 6] = s;
  __syncthreads();
  if (tid == 0) bsum[b] = ws[0] + ws[1] + ws[2] + ws[3];
}

// ---------------- pass 2b: exclusive scan of 98 block sums ----------------
__global__ __launch_bounds__(128) void bscan_kernel(const int* __restrict__ bsum,
                                                    int* __restrict__ bpre) {
  const int t = threadIdx.x;
  const int lane = t & 63, wave = t >> 6;
  int v = (t < SCAN_NB) ? bsum[t] : 0;
  int incl = v;
  for (int d = 1; d < 64; d <<= 1) {
    int q = __shfl_up(incl, d, 64);
    if (lane >= d) incl += q;
  }
  __shared__ int wtot[2];
  if (lane == 63) wtot[wave] = incl;
  __syncthreads();
  int add = (wave == 1) ? wtot[0] : 0;
  if (t < SCAN_NB) bpre[t] = incl - v + add;
}

// ---------------- pass 2c: write offsets + cursor ----------------
__global__ __launch_bounds__(256) void offsets_kernel(const int* __restrict__ hist,
                                                      const int* __restrict__ bpre,
                                                      int* __restrict__ offsets,
                                                      int* __restrict__ cursor) {
  const int b = blockIdx.x, tid = threadIdx.x;
  const int base = b * SCAN_BS + tid * 4;
  const int lane = tid & 63, wave = tid >> 6;
  int4 v = make_int4(0, 0, 0, 0);
  if (base + 3 < NN) v = *reinterpret_cast<const int4*>(&hist[base]);
  else {
    int t[4] = {0, 0, 0, 0};
    for (int k = 0; k < 4; ++k) if (base + k < NN) t[k] = hist[base + k];
    v = make_int4(t[0], t[1], t[2], t[3]);
  }
  const int tsum = v.x + v.y + v.z + v.w;
  int incl = tsum;
  for (int d = 1; d < 64; d <<= 1) {
    int q = __shfl_up(incl, d, 64);
    if (lane >= d) incl += q;
  }
  __shared__ int ws[4];
  __shared__ int wpre[4];
  if (lane == 63) ws[wave] = incl;
  __syncthreads();
  if (tid == 0) {
    int r = 0;
    for (int w = 0; w < 4; ++w) { wpre[w] = r; r += ws[w]; }
  }
  __syncthreads();
  int run = bpre[b] + wpre[wave] + incl - tsum;
  int vals[4] = {v.x, v.y, v.z, v.w};
  for (int k = 0; k < 4; ++k) {
    int i = base + k;
    if (i < NN) { offsets[i] = run; cursor[i] = run; run += vals[k]; }
  }
}

// ---------------- pass 3: build permutation ----------------
__global__ __launch_bounds__(256) void permute_kernel(const int* __restrict__ src,
                                                      int* __restrict__ cursor,
                                                      int* __restrict__ perm) {
  int e = blockIdx.x * 256 + threadIdx.x;
  if (e >= NE) return;
  int s = src[e];
  int pos = atomicAdd(&cursor[s], 1);
  perm[pos] = e;
}

// ---------------- pass 4: per-node gather + mean, 1 wave/node, 4 edges/iter ----------------
__global__ __launch_bounds__(256) void gather_mean_kernel(
    const float* __restrict__ ea, const int* __restrict__ perm,
    const int* __restrict__ hist, const int* __restrict__ offsets,
    unsigned short* __restrict__ mean) {
  const int node = (blockIdx.x * 256 + threadIdx.x) >> 6;
  const int lane = threadIdx.x & 63;
  if (node >= NN) return;
  const int g = lane >> 4;      // edge slot 0..3
  const int c = lane & 15;      // float4 column, active if <12
  const int deg = hist[node];
  const int off = offsets[node];

  float4 acc = make_float4(0.f, 0.f, 0.f, 0.f);
  if (c < 12) {
    const float* bc = ea + (size_t)c * 4;
    int j = g;
    for (; j + 4 < deg; j += 8) {
      int e0 = perm[off + j];
      int e1 = perm[off + j + 4];
      float4 v0 = *reinterpret_cast<const float4*>(bc + (size_t)e0 * EDGE_D);
      float4 v1 = *reinterpret_cast<const float4*>(bc + (size_t)e1 * EDGE_D);
      acc.x += v0.x + v1.x;
      acc.y += v0.y + v1.y;
      acc.z += v0.z + v1.z;
      acc.w += v0.w + v1.w;
    }
    if (j < deg) {
      int e0 = perm[off + j];
      float4 v0 = *reinterpret_cast<const float4*>(bc + (size_t)e0 * EDGE_D);
      acc.x += v0.x; acc.y += v0.y; acc.z += v0.z; acc.w += v0.w;
    }
  }
  // reduce over the 4 edge-slot groups (lane offsets 16/32/48 share same c)
#pragma unroll
  for (int d = 32; d >= 16; d >>= 1) {
    acc.x += __shfl_xor(acc.x, d, 64);
    acc.y += __shfl_xor(acc.y, d, 64);
    acc.z += __shfl_xor(acc.z, d, 64);
    acc.w += __shfl_xor(acc.w, d, 64);
  }
  if (lane < 12) {
    float inv = (deg > 0) ? 1.0f / (float)deg : 0.0f;
    st4(&mean[(size_t)node * EDGE_D + lane * 4],
        make_float4(acc.x * inv, acc.y * inv, acc.z * inv, acc.w * inv));
  }
}

// ---------------- pass 5: fused concat + 3-layer MLP (MFMA) ----------------
__global__ __launch_bounds__(256) void mlp_kernel(
    const float* __restrict__ x, const unsigned short* __restrict__ mean,
    const float* __restrict__ u, const int* __restrict__ batch,
    const float* __restrict__ W1, const float* __restrict__ b1,
    const float* __restrict__ W2, const float* __restrict__ b2,
    const float* __restrict__ W3, const float* __restrict__ b3,
    float* __restrict__ out) {
  __shared__ unsigned short act0[BM][S0];
  __shared__ unsigned short act1[BM][S1];

  const int tid = threadIdx.x;
  const int lane = tid & 63;
  const int wid = tid >> 6;
  const int lr = lane & 15;
  const int lg = lane >> 4;
  const int node0 = blockIdx.x * BM;

  const bf16x8 az = {0, 0, 0, 0, 0, 0, 0, 0};

  for (int i = tid; i < BM * (NODE_D / 4); i += 256) {
    int r = i >> 4, q = i & 15;
    int node = node0 + r;
    float4 v = make_float4(0.f, 0.f, 0.f, 0.f);
    if (node < NN) v = reinterpret_cast<const float4*>(x)[(size_t)node * 16 + q];
    st4(&act0[r][q * 4], v);
  }
  for (int i = tid; i < BM * (EDGE_D / 4); i += 256) {
    int r = i / 12, q = i - r * 12;
    int node = node0 + r;
    uint2 v = make_uint2(0, 0);
    if (node < NN) v = *reinterpret_cast<const uint2*>(&mean[(size_t)node * EDGE_D + q * 4]);
    *reinterpret_cast<uint2*>(&act0[r][NODE_D + q * 4]) = v;
  }
  for (int i = tid; i < BM * (U_D / 4); i += 256) {
    int r = i >> 3, q = i & 7;
    int node = node0 + r;
    float4 v = make_float4(0.f, 0.f, 0.f, 0.f);
    if (node < NN) {
      int b = batch[node];
      v = reinterpret_cast<const float4*>(u)[(size_t)b * 8 + q];
    }
    st4(&act0[r][NODE_D + EDGE_D + q * 4], v);
  }
  __syncthreads();

  // ---- layer 1 ----
  {
    const int n0 = wid * 32;
    bf16x8 wf[5][2];
#pragma unroll
    for (int t = 0; t < 5; ++t) {
#pragma unroll
      for (int nf = 0; nf < 2; ++nf) {
        const int kb = t * 32 + lg * 8;
        const int n = n0 + nf * 16 + lr;
        bf16x8 r = az;
#pragma unroll
        for (int j = 0; j < 8; ++j) {
          int k = kb + j;
          if (k < IN_D) r[j] = f2bs(W1[(size_t)k * HID + n]);
        }
        wf[t][nf] = r;
      }
    }
    float bias0 = b1[n0 + lr], bias1 = b1[n0 + 16 + lr];
    f32x4 acc[4][2];
#pragma unroll
    for (int mf = 0; mf < 4; ++mf) {
      acc[mf][0] = (f32x4){bias0, bias0, bias0, bias0};
      acc[mf][1] = (f32x4){bias1, bias1, bias1, bias1};
    }
#pragma unroll
    for (int t = 0; t < 5; ++t) {
#pragma unroll
      for (int mf = 0; mf < 4; ++mf) {
        bf16x8 a;
        if (t < 4) {
          a = *reinterpret_cast<const bf16x8*>(&act0[mf * 16 + lr][t * 32 + lg * 8]);
        } else {
          a = az;
          if (lg < 2)
            a = *reinterpret_cast<const bf16x8*>(&act0[mf * 16 + lr][128 + lg * 8]);
        }
        acc[mf][0] = __builtin_amdgcn_mfma_f32_16x16x32_bf16(a, wf[t][0], acc[mf][0], 0, 0, 0);
        acc[mf][1] = __builtin_amdgcn_mfma_f32_16x16x32_bf16(a, wf[t][1], acc[mf][1], 0, 0, 0);
      }
    }
#pragma unroll
    for (int mf = 0; mf < 4; ++mf)
#pragma unroll
      for (int nf = 0; nf < 2; ++nf)
#pragma unroll
        for (int r = 0; r < 4; ++r)
          act1[mf * 16 + lg * 4 + r][n0 + nf * 16 + lr] =
              (unsigned short)f2bs(fmaxf(acc[mf][nf][r], 0.f));
  }
  __syncthreads();

  // ---- layer 2 ----
  {
    const int n0 = wid * 32;
    bf16x8 wf[4][2];
#pragma unroll
    for (int t = 0; t < 4; ++t) {
#pragma unroll
      for (int nf = 0; nf < 2; ++nf) {
        const int kb = t * 32 + lg * 8;
        const int n = n0 + nf * 16 + lr;
        bf16x8 r;
#pragma unroll
        for (int j = 0; j < 8; ++j) r[j] = f2bs(W2[(size_t)(kb + j) * HID + n]);
        wf[t][nf] = r;
      }
    }
    float bias0 = b2[n0 + lr], bias1 = b2[n0 + 16 + lr];
    f32x4 acc[4][2];
#pragma unroll
    for (int mf = 0; mf < 4; ++mf) {
      acc[mf][0] = (f32x4){bias0, bias0, bias0, bias0};
      acc[mf][1] = (f32x4){bias1, bias1, bias1, bias1};
    }
#pragma unroll
    for (int t = 0; t < 4; ++t) {
#pragma unroll
      for (int mf = 0; mf < 4; ++mf) {
        bf16x8 a = *reinterpret_cast<const bf16x8*>(&act1[mf * 16 + lr][t * 32 + lg * 8]);
        acc[mf][0] = __builtin_amdgcn_mfma_f32_16x16x32_bf16(a, wf[t][0], acc[mf][0], 0, 0, 0);
        acc[mf][1] = __builtin_amdgcn_mfma_f32_16x16x32_bf16(a, wf[t][1], acc[mf][1], 0, 0, 0);
      }
    }
    __syncthreads();
#pragma unroll
    for (int mf = 0; mf < 4; ++mf)
#pragma unroll
      for (int nf = 0; nf < 2; ++nf)
#pragma unroll
        for (int r = 0; r < 4; ++r)
          act0[mf * 16 + lg * 4 + r][n0 + nf * 16 + lr] =
              (unsigned short)f2bs(fmaxf(acc[mf][nf][r], 0.f));
  }
  __syncthreads();

  // ---- layer 3 ----
  {
    const int n0 = wid * 16;
    bf16x8 wf[4];
#pragma unroll
    for (int t = 0; t < 4; ++t) {
      const int kb = t * 32 + lg * 8;
      const int n = n0 + lr;
      bf16x8 r;
#pragma unroll
      for (int j = 0; j < 8; ++j) r[j] = f2bs(W3[(size_t)(kb + j) * OUT_D + n]);
      wf[t] = r;
    }
    float bias = b3[n0 + lr];
    f32x4 acc[4];
#pragma unroll
    for (int mf = 0; mf < 4; ++mf) acc[mf] = (f32x4){bias, bias, bias, bias};
#pragma unroll
    for (int t = 0; t < 4; ++t) {
#pragma unroll
      for (int mf = 0; mf < 4; ++mf) {
        bf16x8 a = *reinterpret_cast<const bf16x8*>(&act0[mf * 16 + lr][t * 32 + lg * 8]);
        acc[mf] = __builtin_amdgcn_mfma_f32_16x16x32_bf16(a, wf[t], acc[mf], 0, 0, 0);
      }
    }
#pragma unroll
    for (int mf = 0; mf < 4; ++mf)
#pragma unroll
      for (int r = 0; r < 4; ++r) {
        int node = node0 + mf * 16 + lg * 4 + r;
        if (node < NN) out[(size_t)node * OUT_D + n0 + lr] = acc[mf][r];
      }
  }
}

extern "C" void kernel_launch(void* const* d_in, const int* in_sizes, int n_in,
                              void* d_out, int out_size, void* d_ws, size_t ws_size,
                              hipStream_t stream) {
  const float* x   = (const float*)d_in[0];
  const int* ei    = (const int*)d_in[1];
  const float* ea  = (const float*)d_in[2];
  const float* u   = (const float*)d_in[3];
  const int* batch = (const int*)d_in[4];
  const float* W1  = (const float*)d_in[5];
  const float* b1  = (const float*)d_in[6];
  const float* W2  = (const float*)d_in[7];
  const float* b2  = (const float*)d_in[8];
  const float* W3  = (const float*)d_in[9];
  const float* b3  = (const float*)d_in[10];
  float* out = (float*)d_out;

  // workspace layout (~17.2 MB)
  unsigned short* mean = (unsigned short*)d_ws;            // NN*48 bf16 (9.6 MB, 16B-aligned)
  int* hist    = (int*)(mean + (size_t)NN * EDGE_D);       // NN (offset 9.6e6 B, 16B-aligned)
  int* offsets = hist + NN;
  int* cursor  = offsets + NN;
  int* perm    = cursor + NN;                              // NE
  int* bsum    = perm + NE;                                // SCAN_NB
  int* bpre    = bsum + SCAN_NB;                           // SCAN_NB

  hipMemsetAsync(hist, 0, NN * sizeof(int), stream);

  hist_kernel<<<(NE + 255) / 256, 256, 0, stream>>>(ei, hist);
  bsum_kernel<<<SCAN_NB, 256, 0, stream>>>(hist, bsum);
  bscan_kernel<<<1, 128, 0, stream>>>(bsum, bpre);
  offsets_kernel<<<SCAN_NB, 256, 0, stream>>>(hist, bpre, offsets, cursor);
  permute_kernel<<<(NE + 255) / 256, 256, 0, stream>>>(ei, cursor, perm);
  gather_mean_kernel<<<(NN * 64 + 255) / 256, 256, 0, stream>>>(ea, perm, hist, offsets, mean);
  mlp_kernel<<<(NN + BM - 1) / BM, 256, 0, stream>>>(x, mean, u, batch,
                                                     W1, b1, W2, b2, W3, b3, out);
}

// Round 5
// 333.046 us; speedup vs baseline: 2.1807x; 1.0200x over previous
//
#include <hip/hip_runtime.h>
#include <hip/hip_bf16.h>

#define NN 100000
#define NE 1600000
#define NODE_D 64
#define EDGE_D 48
#define U_D 32
#define IN_D 144
#define HID 128
#define OUT_D 64
#define BM 64
#define S0 152   // act0 row stride (ushort cols)
#define S1 136   // act1 row stride
#define SCAN_BS 1024
#define SCAN_NB ((NN + SCAN_BS - 1) / SCAN_BS)  // 98

typedef __attribute__((ext_vector_type(8))) short bf16x8;
typedef __attribute__((ext_vector_type(4))) float f32x4;

__device__ __forceinline__ short f2bs(float f) {
  union { __hip_bfloat16 h; short s; } v;
  v.h = __float2bfloat16(f);
  return v.s;
}

__device__ __forceinline__ void st4(unsigned short* p, float4 v) {
  unsigned a = (unsigned)(unsigned short)f2bs(v.x) | ((unsigned)(unsigned short)f2bs(v.y) << 16);
  unsigned b = (unsigned)(unsigned short)f2bs(v.z) | ((unsigned)(unsigned short)f2bs(v.w) << 16);
  *reinterpret_cast<uint2*>(p) = make_uint2(a, b);
}

// ---------------- pass 0: zero the histogram (replaces slow rocclr fill) ----------------
__global__ __launch_bounds__(256) void zero_hist_kernel(int* __restrict__ hist) {
  int i = blockIdx.x * 256 + threadIdx.x;       // int4 index
  int4 z = make_int4(0, 0, 0, 0);
  int base = i * 4;
  if (base + 3 < NN) {
    *reinterpret_cast<int4*>(&hist[base]) = z;
  } else {
    for (int k = 0; k < 4; ++k)
      if (base + k < NN) hist[base + k] = 0;
  }
}

// ---------------- pass 1: histogram of source nodes ----------------
__global__ __launch_bounds__(256) void hist_kernel(const int* __restrict__ src,
                                                   int* __restrict__ hist) {
  int e = blockIdx.x * 256 + threadIdx.x;
  if (e >= NE) return;
  atomicAdd(&hist[src[e]], 1);
}

// ---------------- pass 2a: per-block sums of hist ----------------
__global__ __launch_bounds__(256) void bsum_kernel(const int* __restrict__ hist,
                                                   int* __restrict__ bsum) {
  const int b = blockIdx.x, tid = threadIdx.x;
  const int base = b * SCAN_BS + tid * 4;
  int4 v = make_int4(0, 0, 0, 0);
  if (base + 3 < NN) v = *reinterpret_cast<const int4*>(&hist[base]);
  else {
    int t[4] = {0, 0, 0, 0};
    for (int k = 0; k < 4; ++k) if (base + k < NN) t[k] = hist[base + k];
    v = make_int4(t[0], t[1], t[2], t[3]);
  }
  int s = v.x + v.y + v.z + v.w;
  for (int d = 32; d; d >>= 1) s += __shfl_down(s, d, 64);
  __shared__ int ws[4];
  if ((tid & 63) == 0) ws[tid >> 6] = s;
  __syncthreads();
  if (tid == 0) bsum[b] = ws[0] + ws[1] + ws[2] + ws[3];
}

// ---------------- pass 2b: exclusive scan of 98 block sums ----------------
__global__ __launch_bounds__(128) void bscan_kernel(const int* __restrict__ bsum,
                                                    int* __restrict__ bpre) {
  const int t = threadIdx.x;
  const int lane = t & 63, wave = t >> 6;
  int v = (t < SCAN_NB) ? bsum[t] : 0;
  int incl = v;
  for (int d = 1; d < 64; d <<= 1) {
    int q = __shfl_up(incl, d, 64);
    if (lane >= d) incl += q;
  }
  __shared__ int wtot[2];
  if (lane == 63) wtot[wave] = incl;
  __syncthreads();
  int add = (wave == 1) ? wtot[0] : 0;
  if (t < SCAN_NB) bpre[t] = incl - v + add;
}

// ---------------- pass 2c: write offsets + cursor ----------------
__global__ __launch_bounds__(256) void offsets_kernel(const int* __restrict__ hist,
                                                      const int* __restrict__ bpre,
                                                      int* __restrict__ offsets,
                                                      int* __restrict__ cursor) {
  const int b = blockIdx.x, tid = threadIdx.x;
  const int base = b * SCAN_BS + tid * 4;
  const int lane = tid & 63, wave = tid >> 6;
  int4 v = make_int4(0, 0, 0, 0);
  if (base + 3 < NN) v = *reinterpret_cast<const int4*>(&hist[base]);
  else {
    int t[4] = {0, 0, 0, 0};
    for (int k = 0; k < 4; ++k) if (base + k < NN) t[k] = hist[base + k];
    v = make_int4(t[0], t[1], t[2], t[3]);
  }
  const int tsum = v.x + v.y + v.z + v.w;
  int incl = tsum;
  for (int d = 1; d < 64; d <<= 1) {
    int q = __shfl_up(incl, d, 64);
    if (lane >= d) incl += q;
  }
  __shared__ int ws[4];
  __shared__ int wpre[4];
  if (lane == 63) ws[wave] = incl;
  __syncthreads();
  if (tid == 0) {
    int r = 0;
    for (int w = 0; w < 4; ++w) { wpre[w] = r; r += ws[w]; }
  }
  __syncthreads();
  int run = bpre[b] + wpre[wave] + incl - tsum;
  int vals[4] = {v.x, v.y, v.z, v.w};
  for (int k = 0; k < 4; ++k) {
    int i = base + k;
    if (i < NN) { offsets[i] = run; cursor[i] = run; run += vals[k]; }
  }
}

// ---------------- pass 3: build permutation ----------------
__global__ __launch_bounds__(256) void permute_kernel(const int* __restrict__ src,
                                                      int* __restrict__ cursor,
                                                      int* __restrict__ perm) {
  int e = blockIdx.x * 256 + threadIdx.x;
  if (e >= NE) return;
  int s = src[e];
  int pos = atomicAdd(&cursor[s], 1);
  perm[pos] = e;
}

// ---------------- pass 4: per-node gather + mean, 1 wave/node, 4 edges/iter ----------------
__global__ __launch_bounds__(256) void gather_mean_kernel(
    const float* __restrict__ ea, const int* __restrict__ perm,
    const int* __restrict__ hist, const int* __restrict__ offsets,
    unsigned short* __restrict__ mean) {
  const int node = (blockIdx.x * 256 + threadIdx.x) >> 6;
  const int lane = threadIdx.x & 63;
  if (node >= NN) return;
  const int g = lane >> 4;      // edge slot 0..3
  const int c = lane & 15;      // float4 column, active if <12
  const int deg = hist[node];
  const int off = offsets[node];

  float4 acc = make_float4(0.f, 0.f, 0.f, 0.f);
  if (c < 12) {
    const float* bc = ea + (size_t)c * 4;
    int j = g;
    for (; j + 4 < deg; j += 8) {
      int e0 = perm[off + j];
      int e1 = perm[off + j + 4];
      float4 v0 = *reinterpret_cast<const float4*>(bc + (size_t)e0 * EDGE_D);
      float4 v1 = *reinterpret_cast<const float4*>(bc + (size_t)e1 * EDGE_D);
      acc.x += v0.x + v1.x;
      acc.y += v0.y + v1.y;
      acc.z += v0.z + v1.z;
      acc.w += v0.w + v1.w;
    }
    if (j < deg) {
      int e0 = perm[off + j];
      float4 v0 = *reinterpret_cast<const float4*>(bc + (size_t)e0 * EDGE_D);
      acc.x += v0.x; acc.y += v0.y; acc.z += v0.z; acc.w += v0.w;
    }
  }
#pragma unroll
  for (int d = 32; d >= 16; d >>= 1) {
    acc.x += __shfl_xor(acc.x, d, 64);
    acc.y += __shfl_xor(acc.y, d, 64);
    acc.z += __shfl_xor(acc.z, d, 64);
    acc.w += __shfl_xor(acc.w, d, 64);
  }
  if (lane < 12) {
    float inv = (deg > 0) ? 1.0f / (float)deg : 0.0f;
    st4(&mean[(size_t)node * EDGE_D + lane * 4],
        make_float4(acc.x * inv, acc.y * inv, acc.z * inv, acc.w * inv));
  }
}

// ---------------- pass 5: fused concat + 3-layer MLP (MFMA) ----------------
__global__ __launch_bounds__(256) void mlp_kernel(
    const float* __restrict__ x, const unsigned short* __restrict__ mean,
    const float* __restrict__ u, const int* __restrict__ batch,
    const float* __restrict__ W1, const float* __restrict__ b1,
    const float* __restrict__ W2, const float* __restrict__ b2,
    const float* __restrict__ W3, const float* __restrict__ b3,
    float* __restrict__ out) {
  __shared__ unsigned short act0[BM][S0];
  __shared__ unsigned short act1[BM][S1];

  const int tid = threadIdx.x;
  const int lane = tid & 63;
  const int wid = tid >> 6;
  const int lr = lane & 15;
  const int lg = lane >> 4;
  const int node0 = blockIdx.x * BM;

  const bf16x8 az = {0, 0, 0, 0, 0, 0, 0, 0};

  for (int i = tid; i < BM * (NODE_D / 4); i += 256) {
    int r = i >> 4, q = i & 15;
    int node = node0 + r;
    float4 v = make_float4(0.f, 0.f, 0.f, 0.f);
    if (node < NN) v = reinterpret_cast<const float4*>(x)[(size_t)node * 16 + q];
    st4(&act0[r][q * 4], v);
  }
  for (int i = tid; i < BM * (EDGE_D / 4); i += 256) {
    int r = i / 12, q = i - r * 12;
    int node = node0 + r;
    uint2 v = make_uint2(0, 0);
    if (node < NN) v = *reinterpret_cast<const uint2*>(&mean[(size_t)node * EDGE_D + q * 4]);
    *reinterpret_cast<uint2*>(&act0[r][NODE_D + q * 4]) = v;
  }
  for (int i = tid; i < BM * (U_D / 4); i += 256) {
    int r = i >> 3, q = i & 7;
    int node = node0 + r;
    float4 v = make_float4(0.f, 0.f, 0.f, 0.f);
    if (node < NN) {
      int b = batch[node];
      v = reinterpret_cast<const float4*>(u)[(size_t)b * 8 + q];
    }
    st4(&act0[r][NODE_D + EDGE_D + q * 4], v);
  }
  __syncthreads();

  // ---- layer 1 ----
  {
    const int n0 = wid * 32;
    bf16x8 wf[5][2];
#pragma unroll
    for (int t = 0; t < 5; ++t) {
#pragma unroll
      for (int nf = 0; nf < 2; ++nf) {
        const int kb = t * 32 + lg * 8;
        const int n = n0 + nf * 16 + lr;
        bf16x8 r = az;
#pragma unroll
        for (int j = 0; j < 8; ++j) {
          int k = kb + j;
          if (k < IN_D) r[j] = f2bs(W1[(size_t)k * HID + n]);
        }
        wf[t][nf] = r;
      }
    }
    float bias0 = b1[n0 + lr], bias1 = b1[n0 + 16 + lr];
    f32x4 acc[4][2];
#pragma unroll
    for (int mf = 0; mf < 4; ++mf) {
      acc[mf][0] = (f32x4){bias0, bias0, bias0, bias0};
      acc[mf][1] = (f32x4){bias1, bias1, bias1, bias1};
    }
#pragma unroll
    for (int t = 0; t < 5; ++t) {
#pragma unroll
      for (int mf = 0; mf < 4; ++mf) {
        bf16x8 a;
        if (t < 4) {
          a = *reinterpret_cast<const bf16x8*>(&act0[mf * 16 + lr][t * 32 + lg * 8]);
        } else {
          a = az;
          if (lg < 2)
            a = *reinterpret_cast<const bf16x8*>(&act0[mf * 16 + lr][128 + lg * 8]);
        }
        acc[mf][0] = __builtin_amdgcn_mfma_f32_16x16x32_bf16(a, wf[t][0], acc[mf][0], 0, 0, 0);
        acc[mf][1] = __builtin_amdgcn_mfma_f32_16x16x32_bf16(a, wf[t][1], acc[mf][1], 0, 0, 0);
      }
    }
#pragma unroll
    for (int mf = 0; mf < 4; ++mf)
#pragma unroll
      for (int nf = 0; nf < 2; ++nf)
#pragma unroll
        for (int r = 0; r < 4; ++r)
          act1[mf * 16 + lg * 4 + r][n0 + nf * 16 + lr] =
              (unsigned short)f2bs(fmaxf(acc[mf][nf][r], 0.f));
  }
  __syncthreads();

  // ---- layer 2 ----
  {
    const int n0 = wid * 32;
    bf16x8 wf[4][2];
#pragma unroll
    for (int t = 0; t < 4; ++t) {
#pragma unroll
      for (int nf = 0; nf < 2; ++nf) {
        const int kb = t * 32 + lg * 8;
        const int n = n0 + nf * 16 + lr;
        bf16x8 r;
#pragma unroll
        for (int j = 0; j < 8; ++j) r[j] = f2bs(W2[(size_t)(kb + j) * HID + n]);
        wf[t][nf] = r;
      }
    }
    float bias0 = b2[n0 + lr], bias1 = b2[n0 + 16 + lr];
    f32x4 acc[4][2];
#pragma unroll
    for (int mf = 0; mf < 4; ++mf) {
      acc[mf][0] = (f32x4){bias0, bias0, bias0, bias0};
      acc[mf][1] = (f32x4){bias1, bias1, bias1, bias1};
    }
#pragma unroll
    for (int t = 0; t < 4; ++t) {
#pragma unroll
      for (int mf = 0; mf < 4; ++mf) {
        bf16x8 a = *reinterpret_cast<const bf16x8*>(&act1[mf * 16 + lr][t * 32 + lg * 8]);
        acc[mf][0] = __builtin_amdgcn_mfma_f32_16x16x32_bf16(a, wf[t][0], acc[mf][0], 0, 0, 0);
        acc[mf][1] = __builtin_amdgcn_mfma_f32_16x16x32_bf16(a, wf[t][1], acc[mf][1], 0, 0, 0);
      }
    }
    __syncthreads();
#pragma unroll
    for (int mf = 0; mf < 4; ++mf)
#pragma unroll
      for (int nf = 0; nf < 2; ++nf)
#pragma unroll
        for (int r = 0; r < 4; ++r)
          act0[mf * 16 + lg * 4 + r][n0 + nf * 16 + lr] =
              (unsigned short)f2bs(fmaxf(acc[mf][nf][r], 0.f));
  }
  __syncthreads();

  // ---- layer 3 ----
  {
    const int n0 = wid * 16;
    bf16x8 wf[4];
#pragma unroll
    for (int t = 0; t < 4; ++t) {
      const int kb = t * 32 + lg * 8;
      const int n = n0 + lr;
      bf16x8 r;
#pragma unroll
      for (int j = 0; j < 8; ++j) r[j] = f2bs(W3[(size_t)(kb + j) * OUT_D + n]);
      wf[t] = r;
    }
    float bias = b3[n0 + lr];
    f32x4 acc[4];
#pragma unroll
    for (int mf = 0; mf < 4; ++mf) acc[mf] = (f32x4){bias, bias, bias, bias};
#pragma unroll
    for (int t = 0; t < 4; ++t) {
#pragma unroll
      for (int mf = 0; mf < 4; ++mf) {
        bf16x8 a = *reinterpret_cast<const bf16x8*>(&act0[mf * 16 + lr][t * 32 + lg * 8]);
        acc[mf] = __builtin_amdgcn_mfma_f32_16x16x32_bf16(a, wf[t], acc[mf], 0, 0, 0);
      }
    }
#pragma unroll
    for (int mf = 0; mf < 4; ++mf)
#pragma unroll
      for (int r = 0; r < 4; ++r) {
        int node = node0 + mf * 16 + lg * 4 + r;
        if (node < NN) out[(size_t)node * OUT_D + n0 + lr] = acc[mf][r];
      }
  }
}

extern "C" void kernel_launch(void* const* d_in, const int* in_sizes, int n_in,
                              void* d_out, int out_size, void* d_ws, size_t ws_size,
                              hipStream_t stream) {
  const float* x   = (const float*)d_in[0];
  const int* ei    = (const int*)d_in[1];
  const float* ea  = (const float*)d_in[2];
  const float* u   = (const float*)d_in[3];
  const int* batch = (const int*)d_in[4];
  const float* W1  = (const float*)d_in[5];
  const float* b1  = (const float*)d_in[6];
  const float* W2  = (const float*)d_in[7];
  const float* b2  = (const float*)d_in[8];
  const float* W3  = (const float*)d_in[9];
  const float* b3  = (const float*)d_in[10];
  float* out = (float*)d_out;

  // workspace layout (~17.2 MB)
  unsigned short* mean = (unsigned short*)d_ws;            // NN*48 bf16 (9.6 MB, 16B-aligned)
  int* hist    = (int*)(mean + (size_t)NN * EDGE_D);       // NN
  int* offsets = hist + NN;
  int* cursor  = offsets + NN;
  int* perm    = cursor + NN;                              // NE
  int* bsum    = perm + NE;                                // SCAN_NB
  int* bpre    = bsum + SCAN_NB;                           // SCAN_NB

  zero_hist_kernel<<<(NN / 4 + 255) / 256, 256, 0, stream>>>(hist);
  hist_kernel<<<(NE + 255) / 256, 256, 0, stream>>>(ei, hist);
  bsum_kernel<<<SCAN_NB, 256, 0, stream>>>(hist, bsum);
  bscan_kernel<<<1, 128, 0, stream>>>(bsum, bpre);
  offsets_kernel<<<SCAN_NB, 256, 0, stream>>>(hist, bpre, offsets, cursor);
  permute_kernel<<<(NE + 255) / 256, 256, 0, stream>>>(ei, cursor, perm);
  gather_mean_kernel<<<(NN * 64 + 255) / 256, 256, 0, stream>>>(ea, perm, hist, offsets, mean);
  mlp_kernel<<<(NN + BM - 1) / BM, 256, 0, stream>>>(x, mean, u, batch,
                                                     W1, b1, W2, b2, W3, b3, out);
}

// Round 6
// 330.518 us; speedup vs baseline: 2.1973x; 1.0077x over previous
//
#include <hip/hip_runtime.h>
#include <hip/hip_bf16.h>

#define NN 100000
#define NE 1600000
#define NODE_D 64
#define EDGE_D 48
#define U_D 32
#define IN_D 144
#define HID 128
#define OUT_D 64
#define BM 64
#define S0 152   // act0 row stride (ushort cols)
#define S1 136   // act1 row stride
#define SCAN_BS 1024
#define SCAN_NB ((NN + SCAN_BS - 1) / SCAN_BS)  // 98
#define W1K 160  // padded k-stride of packed W1 (zeros for k>=144)
// packed weight element counts
#define NW1 (HID * W1K)      // 20480
#define NW2 (HID * HID)      // 16384
#define NW3 (OUT_D * HID)    // 8192
#define NWTOT (NW1 + NW2 + NW3)  // 45056

typedef __attribute__((ext_vector_type(8))) short bf16x8;
typedef __attribute__((ext_vector_type(4))) float f32x4;

__device__ __forceinline__ short f2bs(float f) {
  union { __hip_bfloat16 h; short s; } v;
  v.h = __float2bfloat16(f);
  return v.s;
}

__device__ __forceinline__ void st4(unsigned short* p, float4 v) {
  unsigned a = (unsigned)(unsigned short)f2bs(v.x) | ((unsigned)(unsigned short)f2bs(v.y) << 16);
  unsigned b = (unsigned)(unsigned short)f2bs(v.z) | ((unsigned)(unsigned short)f2bs(v.w) << 16);
  *reinterpret_cast<uint2*>(p) = make_uint2(a, b);
}

// ---------------- setup: zero hist (blocks 0..97) + pack weights (blocks 98..) ----------------
__global__ __launch_bounds__(256) void setup_kernel(
    int* __restrict__ hist,
    const float* __restrict__ W1, const float* __restrict__ W2,
    const float* __restrict__ W3, unsigned short* __restrict__ Wp) {
  const int b = blockIdx.x, tid = threadIdx.x;
  if (b < SCAN_NB) {
    int base = b * SCAN_BS + tid * 4;
    if (base + 3 < NN) {
      *reinterpret_cast<int4*>(&hist[base]) = make_int4(0, 0, 0, 0);
    } else {
      for (int k = 0; k < 4; ++k)
        if (base + k < NN) hist[base + k] = 0;
    }
    return;
  }
  int gid = (b - SCAN_NB) * 256 + tid;
  if (gid >= NWTOT) return;
  float v;
  if (gid < NW1) {
    int n = gid / W1K, k = gid - n * W1K;
    v = (k < IN_D) ? W1[(size_t)k * HID + n] : 0.f;
  } else if (gid < NW1 + NW2) {
    int i2 = gid - NW1;
    int n = i2 >> 7, k = i2 & 127;
    v = W2[(size_t)k * HID + n];
  } else {
    int i3 = gid - NW1 - NW2;
    int n = i3 >> 7, k = i3 & 127;
    v = W3[(size_t)k * OUT_D + n];
  }
  Wp[gid] = (unsigned short)f2bs(v);
}

// ---------------- hist: 2 edges/thread ----------------
__global__ __launch_bounds__(256) void hist_kernel(const int* __restrict__ src,
                                                   int* __restrict__ hist) {
  int i = blockIdx.x * 256 + threadIdx.x;
  int2 s = *reinterpret_cast<const int2*>(&src[i * 2]);
  atomicAdd(&hist[s.x], 1);
  atomicAdd(&hist[s.y], 1);
}

// ---------------- scan 2a ----------------
__global__ __launch_bounds__(256) void bsum_kernel(const int* __restrict__ hist,
                                                   int* __restrict__ bsum) {
  const int b = blockIdx.x, tid = threadIdx.x;
  const int base = b * SCAN_BS + tid * 4;
  int4 v = make_int4(0, 0, 0, 0);
  if (base + 3 < NN) v = *reinterpret_cast<const int4*>(&hist[base]);
  else {
    int t[4] = {0, 0, 0, 0};
    for (int k = 0; k < 4; ++k) if (base + k < NN) t[k] = hist[base + k];
    v = make_int4(t[0], t[1], t[2], t[3]);
  }
  int s = v.x + v.y + v.z + v.w;
  for (int d = 32; d; d >>= 1) s += __shfl_down(s, d, 64);
  __shared__ int ws[4];
  if ((tid & 63) == 0) ws[tid >> 6] = s;
  __syncthreads();
  if (tid == 0) bsum[b] = ws[0] + ws[1] + ws[2] + ws[3];
}

// ---------------- scan 2b ----------------
__global__ __launch_bounds__(128) void bscan_kernel(const int* __restrict__ bsum,
                                                    int* __restrict__ bpre) {
  const int t = threadIdx.x;
  const int lane = t & 63, wave = t >> 6;
  int v = (t < SCAN_NB) ? bsum[t] : 0;
  int incl = v;
  for (int d = 1; d < 64; d <<= 1) {
    int q = __shfl_up(incl, d, 64);
    if (lane >= d) incl += q;
  }
  __shared__ int wtot[2];
  if (lane == 63) wtot[wave] = incl;
  __syncthreads();
  int add = (wave == 1) ? wtot[0] : 0;
  if (t < SCAN_NB) bpre[t] = incl - v + add;
}

// ---------------- scan 2c ----------------
__global__ __launch_bounds__(256) void offsets_kernel(const int* __restrict__ hist,
                                                      const int* __restrict__ bpre,
                                                      int* __restrict__ offsets,
                                                      int* __restrict__ cursor) {
  const int b = blockIdx.x, tid = threadIdx.x;
  const int base = b * SCAN_BS + tid * 4;
  const int lane = tid & 63, wave = tid >> 6;
  int4 v = make_int4(0, 0, 0, 0);
  if (base + 3 < NN) v = *reinterpret_cast<const int4*>(&hist[base]);
  else {
    int t[4] = {0, 0, 0, 0};
    for (int k = 0; k < 4; ++k) if (base + k < NN) t[k] = hist[base + k];
    v = make_int4(t[0], t[1], t[2], t[3]);
  }
  const int tsum = v.x + v.y + v.z + v.w;
  int incl = tsum;
  for (int d = 1; d < 64; d <<= 1) {
    int q = __shfl_up(incl, d, 64);
    if (lane >= d) incl += q;
  }
  __shared__ int ws[4];
  __shared__ int wpre[4];
  if (lane == 63) ws[wave] = incl;
  __syncthreads();
  if (tid == 0) {
    int r = 0;
    for (int w = 0; w < 4; ++w) { wpre[w] = r; r += ws[w]; }
  }
  __syncthreads();
  int run = bpre[b] + wpre[wave] + incl - tsum;
  int vals[4] = {v.x, v.y, v.z, v.w};
  for (int k = 0; k < 4; ++k) {
    int i = base + k;
    if (i < NN) { offsets[i] = run; cursor[i] = run; run += vals[k]; }
  }
}

// ---------------- permute: 2 edges/thread, nontemporal scatter ----------------
__global__ __launch_bounds__(256) void permute_kernel(const int* __restrict__ src,
                                                      int* __restrict__ cursor,
                                                      int* __restrict__ perm) {
  int i = blockIdx.x * 256 + threadIdx.x;
  int2 s = *reinterpret_cast<const int2*>(&src[i * 2]);
  int e0 = i * 2, e1 = i * 2 + 1;
  int p0 = atomicAdd(&cursor[s.x], 1);
  __builtin_nontemporal_store(e0, &perm[p0]);
  int p1 = atomicAdd(&cursor[s.y], 1);
  __builtin_nontemporal_store(e1, &perm[p1]);
}

// ---------------- fused gather + concat + 3-layer MLP ----------------
__global__ __launch_bounds__(256) void fused_kernel(
    const float* __restrict__ x, const float* __restrict__ ea,
    const float* __restrict__ u, const int* __restrict__ batch,
    const int* __restrict__ perm, const int* __restrict__ hist,
    const int* __restrict__ offsets, const unsigned short* __restrict__ Wp,
    const float* __restrict__ b1, const float* __restrict__ b2,
    const float* __restrict__ b3, float* __restrict__ out) {
  __shared__ unsigned short act0[BM][S0];
  __shared__ unsigned short act1[BM][S1];

  const int tid = threadIdx.x;
  const int lane = tid & 63;
  const int wid = tid >> 6;
  const int lr = lane & 15;
  const int lg = lane >> 4;
  const int node0 = blockIdx.x * BM;

  const unsigned short* Wp1 = Wp;                 // [HID][W1K]
  const unsigned short* Wp2 = Wp + NW1;           // [HID][HID]
  const unsigned short* Wp3 = Wp + NW1 + NW2;     // [OUT_D][HID]

  const bf16x8 az = {0, 0, 0, 0, 0, 0, 0, 0};

  // ---- gather phase: 16-lane group handles 4 nodes, v_e -> act0 cols 64..111 ----
  {
    const int g = tid >> 4;        // group 0..15
    const int c = tid & 15;        // float4 column (active < 12)
    const int gb = (g & 3) * 16;   // group base lane within wave
    for (int i = 0; i < 4; ++i) {
      const int nl = g * 4 + i;
      const int node = node0 + nl;
      int deg = 0, off = 0;
      if (node < NN) { deg = hist[node]; off = offsets[node]; }
      float4 acc = make_float4(0.f, 0.f, 0.f, 0.f);
      for (int base = 0; base < deg; base += 16) {
        int rem = deg - base;
        int m = rem < 16 ? rem : 16;
        int pv = 0;
        if (c < m) pv = perm[off + base + c];
        int jj = 0;
        for (; jj + 3 < m; jj += 4) {
          int e0 = __shfl(pv, gb + jj, 64);
          int e1 = __shfl(pv, gb + jj + 1, 64);
          int e2 = __shfl(pv, gb + jj + 2, 64);
          int e3 = __shfl(pv, gb + jj + 3, 64);
          if (c < 12) {
            float4 v0 = *reinterpret_cast<const float4*>(ea + (size_t)e0 * EDGE_D + c * 4);
            float4 v1 = *reinterpret_cast<const float4*>(ea + (size_t)e1 * EDGE_D + c * 4);
            float4 v2 = *reinterpret_cast<const float4*>(ea + (size_t)e2 * EDGE_D + c * 4);
            float4 v3 = *reinterpret_cast<const float4*>(ea + (size_t)e3 * EDGE_D + c * 4);
            acc.x += (v0.x + v1.x) + (v2.x + v3.x);
            acc.y += (v0.y + v1.y) + (v2.y + v3.y);
            acc.z += (v0.z + v1.z) + (v2.z + v3.z);
            acc.w += (v0.w + v1.w) + (v2.w + v3.w);
          }
        }
        for (; jj < m; ++jj) {
          int e0 = __shfl(pv, gb + jj, 64);
          if (c < 12) {
            float4 v0 = *reinterpret_cast<const float4*>(ea + (size_t)e0 * EDGE_D + c * 4);
            acc.x += v0.x; acc.y += v0.y; acc.z += v0.z; acc.w += v0.w;
          }
        }
      }
      float inv = (deg > 0) ? 1.0f / (float)deg : 0.0f;
      if (c < 12)
        st4(&act0[nl][NODE_D + c * 4],
            make_float4(acc.x * inv, acc.y * inv, acc.z * inv, acc.w * inv));
    }
  }

  // ---- stage x and u parts of comb ----
  for (int i = tid; i < BM * (NODE_D / 4); i += 256) {
    int r = i >> 4, q = i & 15;
    int node = node0 + r;
    float4 v = make_float4(0.f, 0.f, 0.f, 0.f);
    if (node < NN) v = reinterpret_cast<const float4*>(x)[(size_t)node * 16 + q];
    st4(&act0[r][q * 4], v);
  }
  for (int i = tid; i < BM * (U_D / 4); i += 256) {
    int r = i >> 3, q = i & 7;
    int node = node0 + r;
    float4 v = make_float4(0.f, 0.f, 0.f, 0.f);
    if (node < NN) {
      int b = batch[node];
      v = reinterpret_cast<const float4*>(u)[(size_t)b * 8 + q];
    }
    st4(&act0[r][NODE_D + EDGE_D + q * 4], v);
  }
  __syncthreads();

  // ---- layer 1: [64,144] @ [144,128] + b1, relu -> act1 ----
  {
    const int n0 = wid * 32;
    bf16x8 wf[5][2];
#pragma unroll
    for (int t = 0; t < 5; ++t)
#pragma unroll
      for (int nf = 0; nf < 2; ++nf)
        wf[t][nf] = *reinterpret_cast<const bf16x8*>(
            &Wp1[(size_t)(n0 + nf * 16 + lr) * W1K + t * 32 + lg * 8]);
    float bias0 = b1[n0 + lr], bias1 = b1[n0 + 16 + lr];
    f32x4 acc[4][2];
#pragma unroll
    for (int mf = 0; mf < 4; ++mf) {
      acc[mf][0] = (f32x4){bias0, bias0, bias0, bias0};
      acc[mf][1] = (f32x4){bias1, bias1, bias1, bias1};
    }
#pragma unroll
    for (int t = 0; t < 5; ++t) {
#pragma unroll
      for (int mf = 0; mf < 4; ++mf) {
        bf16x8 a;
        if (t < 4) {
          a = *reinterpret_cast<const bf16x8*>(&act0[mf * 16 + lr][t * 32 + lg * 8]);
        } else {
          a = az;
          if (lg < 2)
            a = *reinterpret_cast<const bf16x8*>(&act0[mf * 16 + lr][128 + lg * 8]);
        }
        acc[mf][0] = __builtin_amdgcn_mfma_f32_16x16x32_bf16(a, wf[t][0], acc[mf][0], 0, 0, 0);
        acc[mf][1] = __builtin_amdgcn_mfma_f32_16x16x32_bf16(a, wf[t][1], acc[mf][1], 0, 0, 0);
      }
    }
#pragma unroll
    for (int mf = 0; mf < 4; ++mf)
#pragma unroll
      for (int nf = 0; nf < 2; ++nf)
#pragma unroll
        for (int r = 0; r < 4; ++r)
          act1[mf * 16 + lg * 4 + r][n0 + nf * 16 + lr] =
              (unsigned short)f2bs(fmaxf(acc[mf][nf][r], 0.f));
  }
  __syncthreads();

  // ---- layer 2: [64,128] @ [128,128] + b2, relu -> act0 ----
  {
    const int n0 = wid * 32;
    bf16x8 wf[4][2];
#pragma unroll
    for (int t = 0; t < 4; ++t)
#pragma unroll
      for (int nf = 0; nf < 2; ++nf)
        wf[t][nf] = *reinterpret_cast<const bf16x8*>(
            &Wp2[(size_t)(n0 + nf * 16 + lr) * HID + t * 32 + lg * 8]);
    float bias0 = b2[n0 + lr], bias1 = b2[n0 + 16 + lr];
    f32x4 acc[4][2];
#pragma unroll
    for (int mf = 0; mf < 4; ++mf) {
      acc[mf][0] = (f32x4){bias0, bias0, bias0, bias0};
      acc[mf][1] = (f32x4){bias1, bias1, bias1, bias1};
    }
#pragma unroll
    for (int t = 0; t < 4; ++t) {
#pragma unroll
      for (int mf = 0; mf < 4; ++mf) {
        bf16x8 a = *reinterpret_cast<const bf16x8*>(&act1[mf * 16 + lr][t * 32 + lg * 8]);
        acc[mf][0] = __builtin_amdgcn_mfma_f32_16x16x32_bf16(a, wf[t][0], acc[mf][0], 0, 0, 0);
        acc[mf][1] = __builtin_amdgcn_mfma_f32_16x16x32_bf16(a, wf[t][1], acc[mf][1], 0, 0, 0);
      }
    }
    __syncthreads();
#pragma unroll
    for (int mf = 0; mf < 4; ++mf)
#pragma unroll
      for (int nf = 0; nf < 2; ++nf)
#pragma unroll
        for (int r = 0; r < 4; ++r)
          act0[mf * 16 + lg * 4 + r][n0 + nf * 16 + lr] =
              (unsigned short)f2bs(fmaxf(acc[mf][nf][r], 0.f));
  }
  __syncthreads();

  // ---- layer 3: [64,128] @ [128,64] + b3 -> out (f32) ----
  {
    const int n0 = wid * 16;
    bf16x8 wf[4];
#pragma unroll
    for (int t = 0; t < 4; ++t)
      wf[t] = *reinterpret_cast<const bf16x8*>(
          &Wp3[(size_t)(n0 + lr) * HID + t * 32 + lg * 8]);
    float bias = b3[n0 + lr];
    f32x4 acc[4];
#pragma unroll
    for (int mf = 0; mf < 4; ++mf) acc[mf] = (f32x4){bias, bias, bias, bias};
#pragma unroll
    for (int t = 0; t < 4; ++t) {
#pragma unroll
      for (int mf = 0; mf < 4; ++mf) {
        bf16x8 a = *reinterpret_cast<const bf16x8*>(&act0[mf * 16 + lr][t * 32 + lg * 8]);
        acc[mf] = __builtin_amdgcn_mfma_f32_16x16x32_bf16(a, wf[t], acc[mf], 0, 0, 0);
      }
    }
#pragma unroll
    for (int mf = 0; mf < 4; ++mf)
#pragma unroll
      for (int r = 0; r < 4; ++r) {
        int node = node0 + mf * 16 + lg * 4 + r;
        if (node < NN) out[(size_t)node * OUT_D + n0 + lr] = acc[mf][r];
      }
  }
}

extern "C" void kernel_launch(void* const* d_in, const int* in_sizes, int n_in,
                              void* d_out, int out_size, void* d_ws, size_t ws_size,
                              hipStream_t stream) {
  const float* x   = (const float*)d_in[0];
  const int* ei    = (const int*)d_in[1];
  const float* ea  = (const float*)d_in[2];
  const float* u   = (const float*)d_in[3];
  const int* batch = (const int*)d_in[4];
  const float* W1  = (const float*)d_in[5];
  const float* b1  = (const float*)d_in[6];
  const float* W2  = (const float*)d_in[7];
  const float* b2  = (const float*)d_in[8];
  const float* W3  = (const float*)d_in[9];
  const float* b3  = (const float*)d_in[10];
  float* out = (float*)d_out;

  // workspace layout (~7.7 MB)
  int* hist    = (int*)d_ws;                               // NN
  int* offsets = hist + NN;                                // NN
  int* cursor  = offsets + NN;                             // NN
  int* perm    = cursor + NN;                              // NE
  int* bsum    = perm + NE;                                // SCAN_NB
  int* bpre    = bsum + SCAN_NB;                           // SCAN_NB
  unsigned short* Wp = (unsigned short*)(bpre + SCAN_NB + 60);  // NWTOT bf16, 16B-aligned

  const int wblocks = (NWTOT + 255) / 256;  // 176
  setup_kernel<<<SCAN_NB + wblocks, 256, 0, stream>>>(hist, W1, W2, W3, Wp);
  hist_kernel<<<NE / 512, 256, 0, stream>>>(ei, hist);
  bsum_kernel<<<SCAN_NB, 256, 0, stream>>>(hist, bsum);
  bscan_kernel<<<1, 128, 0, stream>>>(bsum, bpre);
  offsets_kernel<<<SCAN_NB, 256, 0, stream>>>(hist, bpre, offsets, cursor);
  permute_kernel<<<NE / 512, 256, 0, stream>>>(ei, cursor, perm);
  fused_kernel<<<(NN + BM - 1) / BM, 256, 0, stream>>>(
      x, ea, u, batch, perm, hist, offsets, Wp, b1, b2, b3, out);
}

// Round 7
// 327.977 us; speedup vs baseline: 2.2144x; 1.0077x over previous
//
#include <hip/hip_runtime.h>
#include <hip/hip_bf16.h>

#define NN 100000
#define NE 1600000
#define NODE_D 64
#define EDGE_D 48
#define U_D 32
#define IN_D 144
#define HID 128
#define OUT_D 64
#define BM 64
#define S0 152   // act0 row stride (ushort cols)
#define S1 136   // act1 row stride
#define SCAN_BS 1024
#define SCAN_NB ((NN + SCAN_BS - 1) / SCAN_BS)  // 98
#define W1K 160  // padded k-stride of packed W1 (zeros for k>=144)
#define NW1 (HID * W1K)      // 20480
#define NW2 (HID * HID)      // 16384
#define NW3 (OUT_D * HID)    // 8192
#define NWTOT (NW1 + NW2 + NW3)  // 45056
#define IDCAP 4096           // ids staged in act1 storage (4352 ints available)

typedef __attribute__((ext_vector_type(8))) short bf16x8;
typedef __attribute__((ext_vector_type(4))) float f32x4;

__device__ __forceinline__ short f2bs(float f) {
  union { __hip_bfloat16 h; short s; } v;
  v.h = __float2bfloat16(f);
  return v.s;
}

__device__ __forceinline__ void st4(unsigned short* p, float4 v) {
  unsigned a = (unsigned)(unsigned short)f2bs(v.x) | ((unsigned)(unsigned short)f2bs(v.y) << 16);
  unsigned b = (unsigned)(unsigned short)f2bs(v.z) | ((unsigned)(unsigned short)f2bs(v.w) << 16);
  *reinterpret_cast<uint2*>(p) = make_uint2(a, b);
}

// ---------------- setup: zero hist (blocks 0..97) + pack weights ----------------
__global__ __launch_bounds__(256) void setup_kernel(
    int* __restrict__ hist,
    const float* __restrict__ W1, const float* __restrict__ W2,
    const float* __restrict__ W3, unsigned short* __restrict__ Wp) {
  const int b = blockIdx.x, tid = threadIdx.x;
  if (b < SCAN_NB) {
    int base = b * SCAN_BS + tid * 4;
    if (base + 3 < NN) {
      *reinterpret_cast<int4*>(&hist[base]) = make_int4(0, 0, 0, 0);
    } else {
      for (int k = 0; k < 4; ++k)
        if (base + k < NN) hist[base + k] = 0;
    }
    return;
  }
  int gid = (b - SCAN_NB) * 256 + tid;
  if (gid >= NWTOT) return;
  float v;
  if (gid < NW1) {
    int n = gid / W1K, k = gid - n * W1K;
    v = (k < IN_D) ? W1[(size_t)k * HID + n] : 0.f;
  } else if (gid < NW1 + NW2) {
    int i2 = gid - NW1;
    int n = i2 >> 7, k = i2 & 127;
    v = W2[(size_t)k * HID + n];
  } else {
    int i3 = gid - NW1 - NW2;
    int n = i3 >> 7, k = i3 & 127;
    v = W3[(size_t)k * OUT_D + n];
  }
  Wp[gid] = (unsigned short)f2bs(v);
}

// ---------------- hist: 2 edges/thread ----------------
__global__ __launch_bounds__(256) void hist_kernel(const int* __restrict__ src,
                                                   int* __restrict__ hist) {
  int i = blockIdx.x * 256 + threadIdx.x;
  int2 s = *reinterpret_cast<const int2*>(&src[i * 2]);
  atomicAdd(&hist[s.x], 1);
  atomicAdd(&hist[s.y], 1);
}

// ---------------- scan 2a ----------------
__global__ __launch_bounds__(256) void bsum_kernel(const int* __restrict__ hist,
                                                   int* __restrict__ bsum) {
  const int b = blockIdx.x, tid = threadIdx.x;
  const int base = b * SCAN_BS + tid * 4;
  int4 v = make_int4(0, 0, 0, 0);
  if (base + 3 < NN) v = *reinterpret_cast<const int4*>(&hist[base]);
  else {
    int t[4] = {0, 0, 0, 0};
    for (int k = 0; k < 4; ++k) if (base + k < NN) t[k] = hist[base + k];
    v = make_int4(t[0], t[1], t[2], t[3]);
  }
  int s = v.x + v.y + v.z + v.w;
  for (int d = 32; d; d >>= 1) s += __shfl_down(s, d, 64);
  __shared__ int ws[4];
  if ((tid & 63) == 0) ws[tid >> 6] = s;
  __syncthreads();
  if (tid == 0) bsum[b] = ws[0] + ws[1] + ws[2] + ws[3];
}

// ---------------- scan 2b ----------------
__global__ __launch_bounds__(128) void bscan_kernel(const int* __restrict__ bsum,
                                                    int* __restrict__ bpre) {
  const int t = threadIdx.x;
  const int lane = t & 63, wave = t >> 6;
  int v = (t < SCAN_NB) ? bsum[t] : 0;
  int incl = v;
  for (int d = 1; d < 64; d <<= 1) {
    int q = __shfl_up(incl, d, 64);
    if (lane >= d) incl += q;
  }
  __shared__ int wtot[2];
  if (lane == 63) wtot[wave] = incl;
  __syncthreads();
  int add = (wave == 1) ? wtot[0] : 0;
  if (t < SCAN_NB) bpre[t] = incl - v + add;
}

// ---------------- scan 2c ----------------
__global__ __launch_bounds__(256) void offsets_kernel(const int* __restrict__ hist,
                                                      const int* __restrict__ bpre,
                                                      int* __restrict__ offsets,
                                                      int* __restrict__ cursor) {
  const int b = blockIdx.x, tid = threadIdx.x;
  const int base = b * SCAN_BS + tid * 4;
  const int lane = tid & 63, wave = tid >> 6;
  int4 v = make_int4(0, 0, 0, 0);
  if (base + 3 < NN) v = *reinterpret_cast<const int4*>(&hist[base]);
  else {
    int t[4] = {0, 0, 0, 0};
    for (int k = 0; k < 4; ++k) if (base + k < NN) t[k] = hist[base + k];
    v = make_int4(t[0], t[1], t[2], t[3]);
  }
  const int tsum = v.x + v.y + v.z + v.w;
  int incl = tsum;
  for (int d = 1; d < 64; d <<= 1) {
    int q = __shfl_up(incl, d, 64);
    if (lane >= d) incl += q;
  }
  __shared__ int ws[4];
  __shared__ int wpre[4];
  if (lane == 63) ws[wave] = incl;
  __syncthreads();
  if (tid == 0) {
    int r = 0;
    for (int w = 0; w < 4; ++w) { wpre[w] = r; r += ws[w]; }
  }
  __syncthreads();
  int run = bpre[b] + wpre[wave] + incl - tsum;
  int vals[4] = {v.x, v.y, v.z, v.w};
  for (int k = 0; k < 4; ++k) {
    int i = base + k;
    if (i < NN) { offsets[i] = run; cursor[i] = run; run += vals[k]; }
  }
}

// ---------------- permute: 2 edges/thread, nontemporal scatter ----------------
__global__ __launch_bounds__(256) void permute_kernel(const int* __restrict__ src,
                                                      int* __restrict__ cursor,
                                                      int* __restrict__ perm) {
  int i = blockIdx.x * 256 + threadIdx.x;
  int2 s = *reinterpret_cast<const int2*>(&src[i * 2]);
  int e0 = i * 2, e1 = i * 2 + 1;
  int p0 = atomicAdd(&cursor[s.x], 1);
  __builtin_nontemporal_store(e0, &perm[p0]);
  int p1 = atomicAdd(&cursor[s.y], 1);
  __builtin_nontemporal_store(e1, &perm[p1]);
}

// ---------------- fused gather + concat + 3-layer MLP ----------------
__global__ __launch_bounds__(256) void fused_kernel(
    const float* __restrict__ x, const float* __restrict__ ea,
    const float* __restrict__ u, const int* __restrict__ batch,
    const int* __restrict__ perm, const int* __restrict__ hist,
    const int* __restrict__ offsets, const unsigned short* __restrict__ Wp,
    const float* __restrict__ b1, const float* __restrict__ b2,
    const float* __restrict__ b3, float* __restrict__ out) {
  __shared__ __align__(16) unsigned short act0[BM][S0];
  __shared__ __align__(16) unsigned short act1[BM][S1];

  const int tid = threadIdx.x;
  const int lane = tid & 63;
  const int wid = tid >> 6;
  const int lr = lane & 15;
  const int lg = lane >> 4;
  const int node0 = blockIdx.x * BM;

  const unsigned short* Wp1 = Wp;                 // [HID][W1K]
  const unsigned short* Wp2 = Wp + NW1;           // [HID][HID]
  const unsigned short* Wp3 = Wp + NW1 + NW2;     // [OUT_D][HID]

  const bf16x8 az = {0, 0, 0, 0, 0, 0, 0, 0};

  // ---- stage block's edge-id range into LDS (reuse act1 storage) ----
  int* ids = reinterpret_cast<int*>(&act1[0][0]);  // 4352 ints available
  const int start = offsets[node0];
  const int end = (node0 + BM < NN) ? offsets[node0 + BM] : NE;
  const int L = end - start;
  for (int i = tid; i < L && i < IDCAP; i += 256)
    ids[i] = perm[start + i];

  // ---- stage x and u parts of comb ----
  for (int i = tid; i < BM * (NODE_D / 4); i += 256) {
    int r = i >> 4, q = i & 15;
    int node = node0 + r;
    float4 v = make_float4(0.f, 0.f, 0.f, 0.f);
    if (node < NN) v = reinterpret_cast<const float4*>(x)[(size_t)node * 16 + q];
    st4(&act0[r][q * 4], v);
  }
  for (int i = tid; i < BM * (U_D / 4); i += 256) {
    int r = i >> 3, q = i & 7;
    int node = node0 + r;
    float4 v = make_float4(0.f, 0.f, 0.f, 0.f);
    if (node < NN) {
      int b = batch[node];
      v = reinterpret_cast<const float4*>(u)[(size_t)b * 8 + q];
    }
    st4(&act0[r][NODE_D + EDGE_D + q * 4], v);
  }
  __syncthreads();

  // ---- gather phase: 16-lane group per node, ids from LDS, 4 loads in flight ----
  {
    const int g = tid >> 4;        // group 0..15
    const int c = tid & 15;        // float4 column (active < 12)
    const bool act = (c < 12);
    const float* bc = ea + (size_t)c * 4;
    for (int i = 0; i < 4; ++i) {
      const int nl = g * 4 + i;
      const int node = node0 + nl;
      int deg = 0, sl = 0;
      if (node < NN) { deg = hist[node]; sl = offsets[node] - start; }
      float4 a0 = make_float4(0.f, 0.f, 0.f, 0.f);
      float4 a1 = make_float4(0.f, 0.f, 0.f, 0.f);
      int j = 0;
      for (; j + 3 < deg; j += 4) {
        int p = sl + j;
        int e0 = (p + 0 < IDCAP) ? ids[p + 0] : perm[start + p + 0];
        int e1 = (p + 1 < IDCAP) ? ids[p + 1] : perm[start + p + 1];
        int e2 = (p + 2 < IDCAP) ? ids[p + 2] : perm[start + p + 2];
        int e3 = (p + 3 < IDCAP) ? ids[p + 3] : perm[start + p + 3];
        if (act) {
          float4 v0 = *reinterpret_cast<const float4*>(bc + (size_t)e0 * EDGE_D);
          float4 v1 = *reinterpret_cast<const float4*>(bc + (size_t)e1 * EDGE_D);
          float4 v2 = *reinterpret_cast<const float4*>(bc + (size_t)e2 * EDGE_D);
          float4 v3 = *reinterpret_cast<const float4*>(bc + (size_t)e3 * EDGE_D);
          a0.x += v0.x + v1.x; a0.y += v0.y + v1.y;
          a0.z += v0.z + v1.z; a0.w += v0.w + v1.w;
          a1.x += v2.x + v3.x; a1.y += v2.y + v3.y;
          a1.z += v2.z + v3.z; a1.w += v2.w + v3.w;
        }
      }
      for (; j < deg; ++j) {
        int p = sl + j;
        int e0 = (p < IDCAP) ? ids[p] : perm[start + p];
        if (act) {
          float4 v0 = *reinterpret_cast<const float4*>(bc + (size_t)e0 * EDGE_D);
          a0.x += v0.x; a0.y += v0.y; a0.z += v0.z; a0.w += v0.w;
        }
      }
      float inv = (deg > 0) ? 1.0f / (float)deg : 0.0f;
      if (act && node < NN)
        st4(&act0[nl][NODE_D + c * 4],
            make_float4((a0.x + a1.x) * inv, (a0.y + a1.y) * inv,
                        (a0.z + a1.z) * inv, (a0.w + a1.w) * inv));
    }
  }
  __syncthreads();

  // ---- layer 1: [64,144] @ [144,128] + b1, relu -> act1 ----
  {
    const int n0 = wid * 32;
    bf16x8 wf[5][2];
#pragma unroll
    for (int t = 0; t < 5; ++t)
#pragma unroll
      for (int nf = 0; nf < 2; ++nf)
        wf[t][nf] = *reinterpret_cast<const bf16x8*>(
            &Wp1[(size_t)(n0 + nf * 16 + lr) * W1K + t * 32 + lg * 8]);
    float bias0 = b1[n0 + lr], bias1 = b1[n0 + 16 + lr];
    f32x4 acc[4][2];
#pragma unroll
    for (int mf = 0; mf < 4; ++mf) {
      acc[mf][0] = (f32x4){bias0, bias0, bias0, bias0};
      acc[mf][1] = (f32x4){bias1, bias1, bias1, bias1};
    }
#pragma unroll
    for (int t = 0; t < 5; ++t) {
#pragma unroll
      for (int mf = 0; mf < 4; ++mf) {
        bf16x8 a;
        if (t < 4) {
          a = *reinterpret_cast<const bf16x8*>(&act0[mf * 16 + lr][t * 32 + lg * 8]);
        } else {
          a = az;
          if (lg < 2)
            a = *reinterpret_cast<const bf16x8*>(&act0[mf * 16 + lr][128 + lg * 8]);
        }
        acc[mf][0] = __builtin_amdgcn_mfma_f32_16x16x32_bf16(a, wf[t][0], acc[mf][0], 0, 0, 0);
        acc[mf][1] = __builtin_amdgcn_mfma_f32_16x16x32_bf16(a, wf[t][1], acc[mf][1], 0, 0, 0);
      }
    }
    __syncthreads();  // ids (in act1 storage) no longer needed; safe to overwrite
#pragma unroll
    for (int mf = 0; mf < 4; ++mf)
#pragma unroll
      for (int nf = 0; nf < 2; ++nf)
#pragma unroll
        for (int r = 0; r < 4; ++r)
          act1[mf * 16 + lg * 4 + r][n0 + nf * 16 + lr] =
              (unsigned short)f2bs(fmaxf(acc[mf][nf][r], 0.f));
  }
  __syncthreads();

  // ---- layer 2: [64,128] @ [128,128] + b2, relu -> act0 ----
  {
    const int n0 = wid * 32;
    bf16x8 wf[4][2];
#pragma unroll
    for (int t = 0; t < 4; ++t)
#pragma unroll
      for (int nf = 0; nf < 2; ++nf)
        wf[t][nf] = *reinterpret_cast<const bf16x8*>(
            &Wp2[(size_t)(n0 + nf * 16 + lr) * HID + t * 32 + lg * 8]);
    float bias0 = b2[n0 + lr], bias1 = b2[n0 + 16 + lr];
    f32x4 acc[4][2];
#pragma unroll
    for (int mf = 0; mf < 4; ++mf) {
      acc[mf][0] = (f32x4){bias0, bias0, bias0, bias0};
      acc[mf][1] = (f32x4){bias1, bias1, bias1, bias1};
    }
#pragma unroll
    for (int t = 0; t < 4; ++t) {
#pragma unroll
      for (int mf = 0; mf < 4; ++mf) {
        bf16x8 a = *reinterpret_cast<const bf16x8*>(&act1[mf * 16 + lr][t * 32 + lg * 8]);
        acc[mf][0] = __builtin_amdgcn_mfma_f32_16x16x32_bf16(a, wf[t][0], acc[mf][0], 0, 0, 0);
        acc[mf][1] = __builtin_amdgcn_mfma_f32_16x16x32_bf16(a, wf[t][1], acc[mf][1], 0, 0, 0);
      }
    }
    __syncthreads();
#pragma unroll
    for (int mf = 0; mf < 4; ++mf)
#pragma unroll
      for (int nf = 0; nf < 2; ++nf)
#pragma unroll
        for (int r = 0; r < 4; ++r)
          act0[mf * 16 + lg * 4 + r][n0 + nf * 16 + lr] =
              (unsigned short)f2bs(fmaxf(acc[mf][nf][r], 0.f));
  }
  __syncthreads();

  // ---- layer 3: [64,128] @ [128,64] + b3 -> out (f32) ----
  {
    const int n0 = wid * 16;
    bf16x8 wf[4];
#pragma unroll
    for (int t = 0; t < 4; ++t)
      wf[t] = *reinterpret_cast<const bf16x8*>(
          &Wp3[(size_t)(n0 + lr) * HID + t * 32 + lg * 8]);
    float bias = b3[n0 + lr];
    f32x4 acc[4];
#pragma unroll
    for (int mf = 0; mf < 4; ++mf) acc[mf] = (f32x4){bias, bias, bias, bias};
#pragma unroll
    for (int t = 0; t < 4; ++t) {
#pragma unroll
      for (int mf = 0; mf < 4; ++mf) {
        bf16x8 a = *reinterpret_cast<const bf16x8*>(&act0[mf * 16 + lr][t * 32 + lg * 8]);
        acc[mf] = __builtin_amdgcn_mfma_f32_16x16x32_bf16(a, wf[t], acc[mf], 0, 0, 0);
      }
    }
#pragma unroll
    for (int mf = 0; mf < 4; ++mf)
#pragma unroll
      for (int r = 0; r < 4; ++r) {
        int node = node0 + mf * 16 + lg * 4 + r;
        if (node < NN) out[(size_t)node * OUT_D + n0 + lr] = acc[mf][r];
      }
  }
}

extern "C" void kernel_launch(void* const* d_in, const int* in_sizes, int n_in,
                              void* d_out, int out_size, void* d_ws, size_t ws_size,
                              hipStream_t stream) {
  const float* x   = (const float*)d_in[0];
  const int* ei    = (const int*)d_in[1];
  const float* ea  = (const float*)d_in[2];
  const float* u   = (const float*)d_in[3];
  const int* batch = (const int*)d_in[4];
  const float* W1  = (const float*)d_in[5];
  const float* b1  = (const float*)d_in[6];
  const float* W2  = (const float*)d_in[7];
  const float* b2  = (const float*)d_in[8];
  const float* W3  = (const float*)d_in[9];
  const float* b3  = (const float*)d_in[10];
  float* out = (float*)d_out;

  // workspace layout (~7.7 MB)
  int* hist    = (int*)d_ws;                               // NN
  int* offsets = hist + NN;                                // NN
  int* cursor  = offsets + NN;                             // NN
  int* perm    = cursor + NN;                              // NE
  int* bsum    = perm + NE;                                // SCAN_NB
  int* bpre    = bsum + SCAN_NB;                           // SCAN_NB
  unsigned short* Wp = (unsigned short*)(bpre + SCAN_NB + 60);  // NWTOT bf16, 16B-aligned

  const int wblocks = (NWTOT + 255) / 256;  // 176
  setup_kernel<<<SCAN_NB + wblocks, 256, 0, stream>>>(hist, W1, W2, W3, Wp);
  hist_kernel<<<NE / 512, 256, 0, stream>>>(ei, hist);
  bsum_kernel<<<SCAN_NB, 256, 0, stream>>>(hist, bsum);
  bscan_kernel<<<1, 128, 0, stream>>>(bsum, bpre);
  offsets_kernel<<<SCAN_NB, 256, 0, stream>>>(hist, bpre, offsets, cursor);
  permute_kernel<<<NE / 512, 256, 0, stream>>>(ei, cursor, perm);
  fused_kernel<<<(NN + BM - 1) / BM, 256, 0, stream>>>(
      x, ea, u, batch, perm, hist, offsets, Wp, b1, b2, b3, out);
}

// Round 8
// 312.828 us; speedup vs baseline: 2.3216x; 1.0484x over previous
//
#include <hip/hip_runtime.h>
#include <hip/hip_bf16.h>

#define NN 100000
#define NE 1600000
#define NODE_D 64
#define EDGE_D 48
#define U_D 32
#define IN_D 144
#define HID 128
#define OUT_D 64
#define BM 64
#define S0 152   // act row stride (ushort cols): 304B -> 12-word bank step, ~2-way max
#define SCAN_BS 1024
#define SCAN_NB ((NN + SCAN_BS - 1) / SCAN_BS)  // 98
#define W1K 160  // padded k-stride of packed W1 (zeros for k>=144)
#define NW1 (HID * W1K)      // 20480
#define NW2 (HID * HID)      // 16384
#define NW3 (OUT_D * HID)    // 8192
#define NWTOT (NW1 + NW2 + NW3)  // 45056
#define IDS 1536             // ids LDS capacity (mean 1024 + 16 sigma)

typedef __attribute__((ext_vector_type(8))) short bf16x8;
typedef __attribute__((ext_vector_type(4))) float f32x4;

__device__ __forceinline__ short f2bs(float f) {
  union { __hip_bfloat16 h; short s; } v;
  v.h = __float2bfloat16(f);
  return v.s;
}

__device__ __forceinline__ void st4(unsigned short* p, float4 v) {
  unsigned a = (unsigned)(unsigned short)f2bs(v.x) | ((unsigned)(unsigned short)f2bs(v.y) << 16);
  unsigned b = (unsigned)(unsigned short)f2bs(v.z) | ((unsigned)(unsigned short)f2bs(v.w) << 16);
  *reinterpret_cast<uint2*>(p) = make_uint2(a, b);
}

// ---------------- setup: zero hist (blocks 0..97) + pack weights ----------------
__global__ __launch_bounds__(256) void setup_kernel(
    int* __restrict__ hist,
    const float* __restrict__ W1, const float* __restrict__ W2,
    const float* __restrict__ W3, unsigned short* __restrict__ Wp) {
  const int b = blockIdx.x, tid = threadIdx.x;
  if (b < SCAN_NB) {
    int base = b * SCAN_BS + tid * 4;
    if (base + 3 < NN) {
      *reinterpret_cast<int4*>(&hist[base]) = make_int4(0, 0, 0, 0);
    } else {
      for (int k = 0; k < 4; ++k)
        if (base + k < NN) hist[base + k] = 0;
    }
    return;
  }
  int gid = (b - SCAN_NB) * 256 + tid;
  if (gid >= NWTOT) return;
  float v;
  if (gid < NW1) {
    int n = gid / W1K, k = gid - n * W1K;
    v = (k < IN_D) ? W1[(size_t)k * HID + n] : 0.f;
  } else if (gid < NW1 + NW2) {
    int i2 = gid - NW1;
    int n = i2 >> 7, k = i2 & 127;
    v = W2[(size_t)k * HID + n];
  } else {
    int i3 = gid - NW1 - NW2;
    int n = i3 >> 7, k = i3 & 127;
    v = W3[(size_t)k * OUT_D + n];
  }
  Wp[gid] = (unsigned short)f2bs(v);
}

// ---------------- hist: 2 edges/thread ----------------
__global__ __launch_bounds__(256) void hist_kernel(const int* __restrict__ src,
                                                   int* __restrict__ hist) {
  int i = blockIdx.x * 256 + threadIdx.x;
  int2 s = *reinterpret_cast<const int2*>(&src[i * 2]);
  atomicAdd(&hist[s.x], 1);
  atomicAdd(&hist[s.y], 1);
}

// ---------------- scan 2a ----------------
__global__ __launch_bounds__(256) void bsum_kernel(const int* __restrict__ hist,
                                                   int* __restrict__ bsum) {
  const int b = blockIdx.x, tid = threadIdx.x;
  const int base = b * SCAN_BS + tid * 4;
  int4 v = make_int4(0, 0, 0, 0);
  if (base + 3 < NN) v = *reinterpret_cast<const int4*>(&hist[base]);
  else {
    int t[4] = {0, 0, 0, 0};
    for (int k = 0; k < 4; ++k) if (base + k < NN) t[k] = hist[base + k];
    v = make_int4(t[0], t[1], t[2], t[3]);
  }
  int s = v.x + v.y + v.z + v.w;
  for (int d = 32; d; d >>= 1) s += __shfl_down(s, d, 64);
  __shared__ int ws[4];
  if ((tid & 63) == 0) ws[tid >> 6] = s;
  __syncthreads();
  if (tid == 0) bsum[b] = ws[0] + ws[1] + ws[2] + ws[3];
}

// ---------------- scan 2b ----------------
__global__ __launch_bounds__(128) void bscan_kernel(const int* __restrict__ bsum,
                                                    int* __restrict__ bpre) {
  const int t = threadIdx.x;
  const int lane = t & 63, wave = t >> 6;
  int v = (t < SCAN_NB) ? bsum[t] : 0;
  int incl = v;
  for (int d = 1; d < 64; d <<= 1) {
    int q = __shfl_up(incl, d, 64);
    if (lane >= d) incl += q;
  }
  __shared__ int wtot[2];
  if (lane == 63) wtot[wave] = incl;
  __syncthreads();
  int add = (wave == 1) ? wtot[0] : 0;
  if (t < SCAN_NB) bpre[t] = incl - v + add;
}

// ---------------- scan 2c ----------------
__global__ __launch_bounds__(256) void offsets_kernel(const int* __restrict__ hist,
                                                      const int* __restrict__ bpre,
                                                      int* __restrict__ offsets,
                                                      int* __restrict__ cursor) {
  const int b = blockIdx.x, tid = threadIdx.x;
  const int base = b * SCAN_BS + tid * 4;
  const int lane = tid & 63, wave = tid >> 6;
  int4 v = make_int4(0, 0, 0, 0);
  if (base + 3 < NN) v = *reinterpret_cast<const int4*>(&hist[base]);
  else {
    int t[4] = {0, 0, 0, 0};
    for (int k = 0; k < 4; ++k) if (base + k < NN) t[k] = hist[base + k];
    v = make_int4(t[0], t[1], t[2], t[3]);
  }
  const int tsum = v.x + v.y + v.z + v.w;
  int incl = tsum;
  for (int d = 1; d < 64; d <<= 1) {
    int q = __shfl_up(incl, d, 64);
    if (lane >= d) incl += q;
  }
  __shared__ int ws[4];
  __shared__ int wpre[4];
  if (lane == 63) ws[wave] = incl;
  __syncthreads();
  if (tid == 0) {
    int r = 0;
    for (int w = 0; w < 4; ++w) { wpre[w] = r; r += ws[w]; }
  }
  __syncthreads();
  int run = bpre[b] + wpre[wave] + incl - tsum;
  int vals[4] = {v.x, v.y, v.z, v.w};
  for (int k = 0; k < 4; ++k) {
    int i = base + k;
    if (i < NN) { offsets[i] = run; cursor[i] = run; run += vals[k]; }
  }
}

// ---------------- permute: 2 edges/thread, nontemporal scatter ----------------
__global__ __launch_bounds__(256) void permute_kernel(const int* __restrict__ src,
                                                      int* __restrict__ cursor,
                                                      int* __restrict__ perm) {
  int i = blockIdx.x * 256 + threadIdx.x;
  int2 s = *reinterpret_cast<const int2*>(&src[i * 2]);
  int e0 = i * 2, e1 = i * 2 + 1;
  int p0 = atomicAdd(&cursor[s.x], 1);
  __builtin_nontemporal_store(e0, &perm[p0]);
  int p1 = atomicAdd(&cursor[s.y], 1);
  __builtin_nontemporal_store(e1, &perm[p1]);
}

// ---------------- fused gather + concat + 3-layer MLP (single LDS buffer) ----------------
__global__ __launch_bounds__(256) void fused_kernel(
    const float* __restrict__ x, const float* __restrict__ ea,
    const float* __restrict__ u, const int* __restrict__ batch,
    const int* __restrict__ perm, const int* __restrict__ hist,
    const int* __restrict__ offsets, const unsigned short* __restrict__ Wp,
    const float* __restrict__ b1, const float* __restrict__ b2,
    const float* __restrict__ b3, float* __restrict__ out) {
  __shared__ __align__(16) unsigned short act[BM][S0];  // comb -> h1 -> h2
  __shared__ int ids[IDS];

  const int tid = threadIdx.x;
  const int lane = tid & 63;
  const int wid = tid >> 6;
  const int lr = lane & 15;
  const int lg = lane >> 4;
  const int node0 = blockIdx.x * BM;

  const unsigned short* Wp1 = Wp;                 // [HID][W1K]
  const unsigned short* Wp2 = Wp + NW1;           // [HID][HID]
  const unsigned short* Wp3 = Wp + NW1 + NW2;     // [OUT_D][HID]

  const bf16x8 az = {0, 0, 0, 0, 0, 0, 0, 0};

  // ---- stage block's edge-id range into LDS ----
  const int start = offsets[node0];
  const int end = (node0 + BM < NN) ? offsets[node0 + BM] : NE;
  const int L = end - start;
  for (int i = tid; i < L && i < IDS; i += 256)
    ids[i] = perm[start + i];

  // ---- stage x and u parts of comb ----
  for (int i = tid; i < BM * (NODE_D / 4); i += 256) {
    int r = i >> 4, q = i & 15;
    int node = node0 + r;
    float4 v = make_float4(0.f, 0.f, 0.f, 0.f);
    if (node < NN) v = reinterpret_cast<const float4*>(x)[(size_t)node * 16 + q];
    st4(&act[r][q * 4], v);
  }
  for (int i = tid; i < BM * (U_D / 4); i += 256) {
    int r = i >> 3, q = i & 7;
    int node = node0 + r;
    float4 v = make_float4(0.f, 0.f, 0.f, 0.f);
    if (node < NN) {
      int b = batch[node];
      v = reinterpret_cast<const float4*>(u)[(size_t)b * 8 + q];
    }
    st4(&act[r][NODE_D + EDGE_D + q * 4], v);
  }
  __syncthreads();

  // ---- gather: 16-lane group per node, ids from LDS, 8 loads in flight ----
  {
    const int g = tid >> 4;        // group 0..15
    const int c = tid & 15;        // float4 column (active < 12)
    const bool on = (c < 12);
    const float* bc = ea + (size_t)c * 4;
    for (int i = 0; i < 4; ++i) {
      const int nl = g * 4 + i;
      const int node = node0 + nl;
      int deg = 0, sl = 0;
      if (node < NN) { deg = hist[node]; sl = offsets[node] - start; }
      float4 a0 = make_float4(0.f, 0.f, 0.f, 0.f);
      float4 a1 = make_float4(0.f, 0.f, 0.f, 0.f);
      int j = 0;
      for (; j + 7 < deg; j += 8) {
        int p = sl + j;
        int e0 = (p + 0 < IDS) ? ids[p + 0] : perm[start + p + 0];
        int e1 = (p + 1 < IDS) ? ids[p + 1] : perm[start + p + 1];
        int e2 = (p + 2 < IDS) ? ids[p + 2] : perm[start + p + 2];
        int e3 = (p + 3 < IDS) ? ids[p + 3] : perm[start + p + 3];
        int e4 = (p + 4 < IDS) ? ids[p + 4] : perm[start + p + 4];
        int e5 = (p + 5 < IDS) ? ids[p + 5] : perm[start + p + 5];
        int e6 = (p + 6 < IDS) ? ids[p + 6] : perm[start + p + 6];
        int e7 = (p + 7 < IDS) ? ids[p + 7] : perm[start + p + 7];
        if (on) {
          float4 v0 = *reinterpret_cast<const float4*>(bc + (size_t)e0 * EDGE_D);
          float4 v1 = *reinterpret_cast<const float4*>(bc + (size_t)e1 * EDGE_D);
          float4 v2 = *reinterpret_cast<const float4*>(bc + (size_t)e2 * EDGE_D);
          float4 v3 = *reinterpret_cast<const float4*>(bc + (size_t)e3 * EDGE_D);
          float4 v4 = *reinterpret_cast<const float4*>(bc + (size_t)e4 * EDGE_D);
          float4 v5 = *reinterpret_cast<const float4*>(bc + (size_t)e5 * EDGE_D);
          float4 v6 = *reinterpret_cast<const float4*>(bc + (size_t)e6 * EDGE_D);
          float4 v7 = *reinterpret_cast<const float4*>(bc + (size_t)e7 * EDGE_D);
          a0.x += (v0.x + v1.x) + (v2.x + v3.x);
          a0.y += (v0.y + v1.y) + (v2.y + v3.y);
          a0.z += (v0.z + v1.z) + (v2.z + v3.z);
          a0.w += (v0.w + v1.w) + (v2.w + v3.w);
          a1.x += (v4.x + v5.x) + (v6.x + v7.x);
          a1.y += (v4.y + v5.y) + (v6.y + v7.y);
          a1.z += (v4.z + v5.z) + (v6.z + v7.z);
          a1.w += (v4.w + v5.w) + (v6.w + v7.w);
        }
      }
      for (; j + 3 < deg; j += 4) {
        int p = sl + j;
        int e0 = (p + 0 < IDS) ? ids[p + 0] : perm[start + p + 0];
        int e1 = (p + 1 < IDS) ? ids[p + 1] : perm[start + p + 1];
        int e2 = (p + 2 < IDS) ? ids[p + 2] : perm[start + p + 2];
        int e3 = (p + 3 < IDS) ? ids[p + 3] : perm[start + p + 3];
        if (on) {
          float4 v0 = *reinterpret_cast<const float4*>(bc + (size_t)e0 * EDGE_D);
          float4 v1 = *reinterpret_cast<const float4*>(bc + (size_t)e1 * EDGE_D);
          float4 v2 = *reinterpret_cast<const float4*>(bc + (size_t)e2 * EDGE_D);
          float4 v3 = *reinterpret_cast<const float4*>(bc + (size_t)e3 * EDGE_D);
          a0.x += (v0.x + v1.x) + (v2.x + v3.x);
          a0.y += (v0.y + v1.y) + (v2.y + v3.y);
          a0.z += (v0.z + v1.z) + (v2.z + v3.z);
          a0.w += (v0.w + v1.w) + (v2.w + v3.w);
        }
      }
      for (; j < deg; ++j) {
        int p = sl + j;
        int e0 = (p < IDS) ? ids[p] : perm[start + p];
        if (on) {
          float4 v0 = *reinterpret_cast<const float4*>(bc + (size_t)e0 * EDGE_D);
          a0.x += v0.x; a0.y += v0.y; a0.z += v0.z; a0.w += v0.w;
        }
      }
      float inv = (deg > 0) ? 1.0f / (float)deg : 0.0f;
      if (on && node < NN)
        st4(&act[nl][NODE_D + c * 4],
            make_float4((a0.x + a1.x) * inv, (a0.y + a1.y) * inv,
                        (a0.z + a1.z) * inv, (a0.w + a1.w) * inv));
    }
  }
  __syncthreads();

  // ---- layer 1: [64,144] @ [144,128] + b1, relu ----
  {
    const int n0 = wid * 32;
    bf16x8 wf[5][2];
#pragma unroll
    for (int t = 0; t < 5; ++t)
#pragma unroll
      for (int nf = 0; nf < 2; ++nf)
        wf[t][nf] = *reinterpret_cast<const bf16x8*>(
            &Wp1[(size_t)(n0 + nf * 16 + lr) * W1K + t * 32 + lg * 8]);
    float bias0 = b1[n0 + lr], bias1 = b1[n0 + 16 + lr];
    f32x4 acc[4][2];
#pragma unroll
    for (int mf = 0; mf < 4; ++mf) {
      acc[mf][0] = (f32x4){bias0, bias0, bias0, bias0};
      acc[mf][1] = (f32x4){bias1, bias1, bias1, bias1};
    }
#pragma unroll
    for (int t = 0; t < 5; ++t) {
#pragma unroll
      for (int mf = 0; mf < 4; ++mf) {
        bf16x8 a;
        if (t < 4) {
          a = *reinterpret_cast<const bf16x8*>(&act[mf * 16 + lr][t * 32 + lg * 8]);
        } else {
          a = az;
          if (lg < 2)
            a = *reinterpret_cast<const bf16x8*>(&act[mf * 16 + lr][128 + lg * 8]);
        }
        acc[mf][0] = __builtin_amdgcn_mfma_f32_16x16x32_bf16(a, wf[t][0], acc[mf][0], 0, 0, 0);
        acc[mf][1] = __builtin_amdgcn_mfma_f32_16x16x32_bf16(a, wf[t][1], acc[mf][1], 0, 0, 0);
      }
    }
    __syncthreads();  // all waves done reading comb
#pragma unroll
    for (int mf = 0; mf < 4; ++mf)
#pragma unroll
      for (int nf = 0; nf < 2; ++nf)
#pragma unroll
        for (int r = 0; r < 4; ++r)
          act[mf * 16 + lg * 4 + r][n0 + nf * 16 + lr] =
              (unsigned short)f2bs(fmaxf(acc[mf][nf][r], 0.f));
  }
  __syncthreads();

  // ---- layer 2: [64,128] @ [128,128] + b2, relu ----
  {
    const int n0 = wid * 32;
    bf16x8 wf[4][2];
#pragma unroll
    for (int t = 0; t < 4; ++t)
#pragma unroll
      for (int nf = 0; nf < 2; ++nf)
        wf[t][nf] = *reinterpret_cast<const bf16x8*>(
            &Wp2[(size_t)(n0 + nf * 16 + lr) * HID + t * 32 + lg * 8]);
    float bias0 = b2[n0 + lr], bias1 = b2[n0 + 16 + lr];
    f32x4 acc[4][2];
#pragma unroll
    for (int mf = 0; mf < 4; ++mf) {
      acc[mf][0] = (f32x4){bias0, bias0, bias0, bias0};
      acc[mf][1] = (f32x4){bias1, bias1, bias1, bias1};
    }
#pragma unroll
    for (int t = 0; t < 4; ++t) {
#pragma unroll
      for (int mf = 0; mf < 4; ++mf) {
        bf16x8 a = *reinterpret_cast<const bf16x8*>(&act[mf * 16 + lr][t * 32 + lg * 8]);
        acc[mf][0] = __builtin_amdgcn_mfma_f32_16x16x32_bf16(a, wf[t][0], acc[mf][0], 0, 0, 0);
        acc[mf][1] = __builtin_amdgcn_mfma_f32_16x16x32_bf16(a, wf[t][1], acc[mf][1], 0, 0, 0);
      }
    }
    __syncthreads();  // all waves done reading h1
#pragma unroll
    for (int mf = 0; mf < 4; ++mf)
#pragma unroll
      for (int nf = 0; nf < 2; ++nf)
#pragma unroll
        for (int r = 0; r < 4; ++r)
          act[mf * 16 + lg * 4 + r][n0 + nf * 16 + lr] =
              (unsigned short)f2bs(fmaxf(acc[mf][nf][r], 0.f));
  }
  __syncthreads();

  // ---- layer 3: [64,128] @ [128,64] + b3 -> out (f32) ----
  {
    const int n0 = wid * 16;
    bf16x8 wf[4];
#pragma unroll
    for (int t = 0; t < 4; ++t)
      wf[t] = *reinterpret_cast<const bf16x8*>(
          &Wp3[(size_t)(n0 + lr) * HID + t * 32 + lg * 8]);
    float bias = b3[n0 + lr];
    f32x4 acc[4];
#pragma unroll
    for (int mf = 0; mf < 4; ++mf) acc[mf] = (f32x4){bias, bias, bias, bias};
#pragma unroll
    for (int t = 0; t < 4; ++t) {
#pragma unroll
      for (int mf = 0; mf < 4; ++mf) {
        bf16x8 a = *reinterpret_cast<const bf16x8*>(&act[mf * 16 + lr][t * 32 + lg * 8]);
        acc[mf] = __builtin_amdgcn_mfma_f32_16x16x32_bf16(a, wf[t], acc[mf], 0, 0, 0);
      }
    }
#pragma unroll
    for (int mf = 0; mf < 4; ++mf)
#pragma unroll
      for (int r = 0; r < 4; ++r) {
        int node = node0 + mf * 16 + lg * 4 + r;
        if (node < NN) out[(size_t)node * OUT_D + n0 + lr] = acc[mf][r];
      }
  }
}

extern "C" void kernel_launch(void* const* d_in, const int* in_sizes, int n_in,
                              void* d_out, int out_size, void* d_ws, size_t ws_size,
                              hipStream_t stream) {
  const float* x   = (const float*)d_in[0];
  const int* ei    = (const int*)d_in[1];
  const float* ea  = (const float*)d_in[2];
  const float* u   = (const float*)d_in[3];
  const int* batch = (const int*)d_in[4];
  const float* W1  = (const float*)d_in[5];
  const float* b1  = (const float*)d_in[6];
  const float* W2  = (const float*)d_in[7];
  const float* b2  = (const float*)d_in[8];
  const float* W3  = (const float*)d_in[9];
  const float* b3  = (const float*)d_in[10];
  float* out = (float*)d_out;

  // workspace layout (~7.7 MB)
  int* hist    = (int*)d_ws;                               // NN
  int* offsets = hist + NN;                                // NN
  int* cursor  = offsets + NN;                             // NN
  int* perm    = cursor + NN;                              // NE
  int* bsum    = perm + NE;                                // SCAN_NB
  int* bpre    = bsum + SCAN_NB;                           // SCAN_NB
  unsigned short* Wp = (unsigned short*)(bpre + SCAN_NB + 60);  // NWTOT bf16, 16B-aligned

  const int wblocks = (NWTOT + 255) / 256;  // 176
  setup_kernel<<<SCAN_NB + wblocks, 256, 0, stream>>>(hist, W1, W2, W3, Wp);
  hist_kernel<<<NE / 512, 256, 0, stream>>>(ei, hist);
  bsum_kernel<<<SCAN_NB, 256, 0, stream>>>(hist, bsum);
  bscan_kernel<<<1, 128, 0, stream>>>(bsum, bpre);
  offsets_kernel<<<SCAN_NB, 256, 0, stream>>>(hist, bpre, offsets, cursor);
  permute_kernel<<<NE / 512, 256, 0, stream>>>(ei, cursor, perm);
  fused_kernel<<<(NN + BM - 1) / BM, 256, 0, stream>>>(
      x, ea, u, batch, perm, hist, offsets, Wp, b1, b2, b3, out);
}